// Round 6
// baseline (483.502 us; speedup 1.0000x reference)
//
#include <hip/hip_runtime.h>
#include <hip/hip_bf16.h>
#include <math.h>

typedef __hip_bfloat16 bf16;

__device__ __forceinline__ float b2f(bf16 v){ return __bfloat162float(v); }
__device__ __forceinline__ float eluf(float x){ return x > 0.f ? x : __expf(x) - 1.f; }
__device__ __forceinline__ float lrelu(float x){ return x > 0.f ? x : 0.2f * x; }

// ---------------- dtype detection ----------------
// flag: 0 = bf16 inputs, 1 = fp32 inputs. (Round-2 evidence: bf16.)
__global__ void detect_k(const unsigned short* __restrict__ u16, int n, int* __restrict__ flag){
  int bad = 0;
  for (int k = threadIdx.x; k < n; k += 256){
    int ex = (u16[k] >> 7) & 0xFF;
    if (ex >= 0xC6) bad = 1;
  }
  if (__any(bad) && (threadIdx.x & 63) == 0) atomicOr(flag, 1);
}

// ---------------- unified input conversion to fp32 ----------------
struct ConvDesc {
  const void* src[21];
  int off[22];
};

__global__ void convert_all_k(ConvDesc d, float* __restrict__ out,
                              const int* __restrict__ flag, int total){
  int i = blockIdx.x * blockDim.x + threadIdx.x;
  if (i >= total) return;
  int a = 0;
  while (i >= d.off[a + 1]) ++a;
  int j = i - d.off[a];
  float v;
  if (*flag) v = ((const float*)d.src[a])[j];
  else       v = b2f(((const bf16*)d.src[a])[j]);
  out[i] = v;
}

// ---------------- CSR build (dst identical for all 4 layers) ----------------

__global__ void count_edges_k(const int* __restrict__ ei, int* __restrict__ counts, int E, int n){
  int e = blockIdx.x * blockDim.x + threadIdx.x;
  if (e >= E + n) return;
  int d = (e < E) ? ei[E + e] : (e - E);
  atomicAdd(&counts[d], 1);
}

__global__ void scan_k(const int* __restrict__ counts, int* __restrict__ row_ptr, int n){
  __shared__ int psum[1024];
  int t = threadIdx.x;
  int chunk = (n + 1023) >> 10;
  int beg = t * chunk;
  int end = beg + chunk; if (end > n) end = n;
  int s = 0;
  for (int i = beg; i < end; ++i) s += counts[i];
  psum[t] = s;
  __syncthreads();
  for (int off = 1; off < 1024; off <<= 1){
    int v = (t >= off) ? psum[t - off] : 0;
    __syncthreads();
    psum[t] += v;
    __syncthreads();
  }
  int run = psum[t] - s;
  for (int i = beg; i < end; ++i){ row_ptr[i] = run; run += counts[i]; }
  if (beg < n && end == n) row_ptr[n] = run;
}

__global__ void scatter_k(const int* __restrict__ ei, const int* __restrict__ row_ptr,
                          int* __restrict__ fill, int* __restrict__ esrc, int E, int n){
  int e = blockIdx.x * blockDim.x + threadIdx.x;
  if (e >= E + n) return;
  int s, d;
  if (e < E){ s = ei[e]; d = ei[E + e]; } else { s = e - E; d = s; }
  int pos = row_ptr[d] + atomicAdd(&fill[d], 1);
  esrc[pos] = s;
}

// ---------------- tiled linear, K-chunked, W in LDS, optional bias+ELU ------
// Y[n, mb0:mb0+MB] = act(X[n,K] @ W[K, mb0:mb0+MB] + bias).  64-node tile,
// K staged in KC=64 chunks so LDS stays at ~33KB even for K=256.
template<int K, int M, int MB, bool ELU>
__global__ void linear_e_k(const float* __restrict__ X, const float* __restrict__ W,
                           const float* __restrict__ bias, float* __restrict__ Y, int n){
  constexpr int KC  = (K > 64) ? 64 : K;
  constexpr int MQ  = MB / 4;
  constexpr int NPW = 64 / MQ;
  constexpr int ITERS = 64 / (4 * NPW);
  __shared__ float wl[KC * MB];
  __shared__ float xt[KC][65];
  int base = blockIdx.x * 64;
  int mb0  = blockIdx.y * MB;
  int t = threadIdx.x;
  int lane = t & 63, wv = t >> 6;
  int jj = lane % MQ;
  int no = lane / MQ;
  float ax[ITERS], ay[ITERS], az[ITERS], aw[ITERS];
#pragma unroll
  for (int it = 0; it < ITERS; ++it){ ax[it] = ay[it] = az[it] = aw[it] = 0.f; }

  for (int kb = 0; kb < K; kb += KC){
    for (int q = t; q < KC * MQ; q += 256){
      int k = q / MQ, j = q - k * MQ;
      ((float4*)wl)[q] = ((const float4*)(W + (size_t)(kb + k) * M + mb0))[j];
    }
    for (int q = t; q < 64 * (KC / 4); q += 256){
      int node = q / (KC / 4);
      int k4 = q - node * (KC / 4);
      float4 v = make_float4(0.f, 0.f, 0.f, 0.f);
      if (base + node < n) v = *(const float4*)(X + (size_t)(base + node) * K + kb + k4 * 4);
      xt[k4 * 4 + 0][node] = v.x;
      xt[k4 * 4 + 1][node] = v.y;
      xt[k4 * 4 + 2][node] = v.z;
      xt[k4 * 4 + 3][node] = v.w;
    }
    __syncthreads();
#pragma unroll
    for (int it = 0; it < ITERS; ++it){
      int nl = (it * 4 + wv) * NPW + no;
#pragma unroll 8
      for (int k = 0; k < KC; ++k){
        float xv = xt[k][nl];
        float4 w = ((const float4*)wl)[k * MQ + jj];
        ax[it] += xv * w.x; ay[it] += xv * w.y; az[it] += xv * w.z; aw[it] += xv * w.w;
      }
    }
    __syncthreads();
  }
  float4 b = make_float4(0.f, 0.f, 0.f, 0.f);
  if (bias) b = ((const float4*)(bias + mb0))[jj];
#pragma unroll
  for (int it = 0; it < ITERS; ++it){
    int nl = (it * 4 + wv) * NPW + no;
    int node = base + nl;
    if (node < n){
      float vx = ax[it] + b.x, vy = ay[it] + b.y, vz = az[it] + b.z, vw = aw[it] + b.w;
      if (ELU){ vx = eluf(vx); vy = eluf(vy); vz = eluf(vz); vw = eluf(vw); }
      ((float4*)(Y + (size_t)node * M + mb0))[jj] = make_float4(vx, vy, vz, vw);
    }
  }
}

// asrc[n*H+h] = dot(h[n,h,:], a_src[h,:]); float4 loads. (layers 1-3)
__global__ void alpha_k(const float* __restrict__ hlin, const float* __restrict__ a_src,
                        const float* __restrict__ a_dst, float* __restrict__ asrc,
                        float* __restrict__ adst, int n, int H, int C){
  int i = blockIdx.x * blockDim.x + threadIdx.x;
  if (i >= n * H) return;
  int node = i / H;
  int head = i - node * H;
  const float4* hp  = (const float4*)(hlin + (size_t)node * H * C + head * C);
  const float4* asp = (const float4*)(a_src + head * C);
  const float4* adp = (const float4*)(a_dst + head * C);
  float s1 = 0.f, s2 = 0.f;
  for (int c = 0; c < C / 4; ++c){
    float4 v = hp[c], a = asp[c], d = adp[c];
    s1 += v.x * a.x + v.y * a.y + v.z * a.z + v.w * a.w;
    s2 += v.x * d.x + v.y * d.y + v.z * d.z + v.w * d.w;
  }
  asrc[i] = s1;
  adst[i] = s2;
}

// ---------------- layer-4 algebraic restructure ----------------
// av[h*64+k] = sum_c W4[k, h*64+c] * a4[h,c]   (fold W4 into attention vecs)
__global__ void av_k(const float* __restrict__ W4, const float* __restrict__ as4,
                     const float* __restrict__ ad4, float* __restrict__ avs,
                     float* __restrict__ avd){
  int t = threadIdx.x;            // t = h*64+k
  int h = t >> 6, k = t & 63;
  const float* wr = W4 + (size_t)k * 256 + h * 64;
  const float* sr = as4 + h * 64;
  const float* dr = ad4 + h * 64;
  float s1 = 0.f, s2 = 0.f;
  for (int c = 0; c < 64; ++c){ float w = wr[c]; s1 += w * sr[c]; s2 += w * dr[c]; }
  avs[t] = s1;
  avd[t] = s2;
}

// alpha4 from h3 directly: asrc[n*4+h] = h3[n,:] . avs[h,:]
__global__ void alpha4_k(const float* __restrict__ h3, const float* __restrict__ avs,
                         const float* __restrict__ avd, float* __restrict__ asrc,
                         float* __restrict__ adst, int n){
  int i = blockIdx.x * blockDim.x + threadIdx.x;
  if (i >= n * 4) return;
  int node = i >> 2, head = i & 3;
  const float4* hp = (const float4*)(h3 + (size_t)node * 64);
  const float4* sp = (const float4*)(avs + head * 64);
  const float4* dp = (const float4*)(avd + head * 64);
  float s1 = 0.f, s2 = 0.f;
#pragma unroll 4
  for (int q = 0; q < 16; ++q){
    float4 v = hp[q], a = sp[q], d = dp[q];
    s1 += v.x * a.x + v.y * a.y + v.z * a.z + v.w * a.w;
    s2 += v.x * d.x + v.y * d.y + v.z * d.z + v.w * d.w;
  }
  asrc[i] = s1;
  adst[i] = s2;
}

// Wz[h*64+k][c] = 0.25 * W4[k][h*64+c]  (head-mean folded; 256x64)
__global__ void wz_k(const float* __restrict__ W4, float* __restrict__ Wz){
  int t = blockIdx.x * 256 + threadIdx.x;   // t < 16384
  int r = t >> 6, c = t & 63;
  int h = r >> 6, k = r & 63;
  Wz[(size_t)r * 64 + c] = 0.25f * W4[(size_t)k * 256 + h * 64 + c];
}

// Layer-4 gather: z[n, h*64+c] = sum_e w_e h3[s_e, c] / sw_h.
// One wave per node. Weights computed EDGE-BATCHED: lane = head*16 + j covers
// 16 edges x 4 heads per exp instruction (was 64-way redundant, 4 exp/edge).
// Weights & src indices broadcast via __shfl; h3 row loads stay coalesced.
__global__ void aggz_k(const float* __restrict__ h3, const float* __restrict__ asrc,
                       const float* __restrict__ adst, const int* __restrict__ row_ptr,
                       const int* __restrict__ esrc, float* __restrict__ z, int n){
  int node = (blockIdx.x * blockDim.x + threadIdx.x) >> 6;
  if (node >= n) return;
  int lane = threadIdx.x & 63;
  int h = lane >> 4, j = lane & 15;
  int beg = row_ptr[node], end = row_ptr[node + 1];
  float4 adv = *(const float4*)(adst + (size_t)node * 4);
  float adh = h == 0 ? adv.x : h == 1 ? adv.y : h == 2 ? adv.z : adv.w;
  // phase 1: per-head max (16 lanes per head, strided edges)
  float m = -INFINITY;
  for (int p = beg + j; p < end; p += 16)
    m = fmaxf(m, lrelu(asrc[esrc[p] * 4 + h] + adh));
  m = fmaxf(m, __shfl_xor(m, 1));
  m = fmaxf(m, __shfl_xor(m, 2));
  m = fmaxf(m, __shfl_xor(m, 4));
  m = fmaxf(m, __shfl_xor(m, 8));   // every lane in group h now holds m_h
  // phase 2: batched exp + accumulate; lane owns channel c = lane
  float acc0 = 0.f, acc1 = 0.f, acc2 = 0.f, acc3 = 0.f, swp = 0.f;
  for (int b0 = beg; b0 < end; b0 += 16){
    int p = b0 + j;
    float w = 0.f; int s = 0;
    if (p < end){ s = esrc[p]; w = __expf(lrelu(asrc[s * 4 + h] + adh) - m); }
    swp += w;
    int cnt = end - b0; if (cnt > 16) cnt = 16;
    for (int i = 0; i < cnt; ++i){
      int   si = __shfl(s, i);          // group 0's lane i holds s_i
      float hv = h3[(size_t)si * 64 + lane];
      float w0 = __shfl(w, i);
      float w1 = __shfl(w, 16 + i);
      float w2 = __shfl(w, 32 + i);
      float w3 = __shfl(w, 48 + i);
      acc0 += hv * w0; acc1 += hv * w1; acc2 += hv * w2; acc3 += hv * w3;
    }
  }
  swp += __shfl_xor(swp, 1);
  swp += __shfl_xor(swp, 2);
  swp += __shfl_xor(swp, 4);
  swp += __shfl_xor(swp, 8);          // sw_h in every lane of group h
  float sw0 = __shfl(swp, 0), sw1 = __shfl(swp, 16);
  float sw2 = __shfl(swp, 32), sw3 = __shfl(swp, 48);
  size_t zb = (size_t)node * 256;
  z[zb + lane]        = acc0 / sw0;
  z[zb + 64 + lane]   = acc1 / sw1;
  z[zb + 128 + lane]  = acc2 / sw2;
  z[zb + 192 + lane]  = acc3 / sw3;
}

// Layers 1-3: H=8, C=8. One wave per dst node; lane = head*8+j = channel.
__global__ void agg8_k(const float* __restrict__ hlin, const float* __restrict__ asrc,
                       const float* __restrict__ adst, const int* __restrict__ row_ptr,
                       const int* __restrict__ esrc, const float* __restrict__ bias,
                       float* __restrict__ hout, int n){
  int node = (blockIdx.x * blockDim.x + threadIdx.x) >> 6;
  if (node >= n) return;
  int lane = threadIdx.x & 63;
  int head = lane >> 3;
  int j = lane & 7;
  int beg = row_ptr[node], end = row_ptr[node + 1];
  float ad = adst[node * 8 + head];
  float m = -INFINITY;
  for (int p = beg + j; p < end; p += 8){
    int s = esrc[p];
    m = fmaxf(m, lrelu(asrc[s * 8 + head] + ad));
  }
  m = fmaxf(m, __shfl_xor(m, 1));
  m = fmaxf(m, __shfl_xor(m, 2));
  m = fmaxf(m, __shfl_xor(m, 4));
  float acc = 0.f, sw = 0.f;
  for (int p = beg; p < end; ++p){
    int s = esrc[p];
    float w = __expf(lrelu(asrc[s * 8 + head] + ad) - m);
    sw += w;
    acc += hlin[(size_t)s * 64 + lane] * w;
  }
  float o = acc / sw + bias[lane];
  hout[(size_t)node * 64 + lane] = eluf(o);
}

// ---------------- pooling + head ----------------

__global__ void pool_k(const float* __restrict__ h, const int* __restrict__ fidx,
                       const int* __restrict__ flag_arr, float* __restrict__ fp, int m){
  __shared__ float acc[512];
  for (int t = threadIdx.x; t < 512; t += blockDim.x) acc[t] = 0.f;
  __syncthreads();
  int lane = threadIdx.x & 63;
  int wave = (blockIdx.x * blockDim.x + threadIdx.x) >> 6;
  int nwaves = (gridDim.x * blockDim.x) >> 6;
  for (int i = wave; i < m; i += nwaves){
    int g = flag_arr[i];
    int node = fidx[i];
    atomicAdd(&acc[g * 64 + lane], h[(size_t)node * 64 + lane]);
  }
  __syncthreads();
  for (int t = threadIdx.x; t < 512; t += blockDim.x)
    atomicAdd(&fp[t], acc[t]);
}

__global__ void final_k(const float* __restrict__ fp, const float* __restrict__ h,
                        const int* __restrict__ dec,
                        const float* __restrict__ Wp, const float* __restrict__ Wt,
                        const float* __restrict__ Wo, const float* __restrict__ bo,
                        void* __restrict__ out, const int* __restrict__ dflag){
  int g = threadIdx.x >> 6;
  int j = threadIdx.x & 63;
  const float* fr = fp + g * 64;
  const float* tr = h + (size_t)dec[g] * 64;
  float a = 0.f, b = 0.f;
  for (int k = 0; k < 64; ++k){
    a += fr[k] * Wp[k * 64 + j];
    b += tr[k] * Wt[k * 64 + j];
  }
  float v = eluf(a) * Wo[j] + eluf(b) * Wo[64 + j];
  for (int off = 32; off > 0; off >>= 1) v += __shfl_down(v, off);
  if (j == 0){
    float r = v + bo[0];
    if (*dflag) ((float*)out)[g] = r;
    else        ((bf16*)out)[g] = __float2bfloat16(r);
  }
}

// ---------------- launch ----------------

extern "C" void kernel_launch(void* const* d_in, const int* in_sizes, int n_in,
                              void* d_out, int out_size, void* d_ws, size_t ws_size,
                              hipStream_t stream) {
  const int*  ei    = (const int*)d_in[1];
  const int*  fidx  = (const int*)d_in[2];
  const int*  flagg = (const int*)d_in[3];
  const int*  dec   = (const int*)d_in[4];

  const int N = in_sizes[0] / 16;   // 20000
  const int E = in_sizes[1] / 2;    // 320000
  const int M = in_sizes[2];        // 8000
  const int ET = E + N;

  const int fidxs[21] = {0,5,6,7,8,9,10,11,12,13,14,15,16,17,18,19,20,21,22,23,24};
  ConvDesc cd;
  int tot = 0;
  for (int k = 0; k < 21; ++k){
    cd.src[k] = d_in[fidxs[k]];
    cd.off[k] = tot;
    tot += in_sizes[fidxs[k]];
  }
  cd.off[21] = tot;

  char* p = (char*)d_ws;
  auto carve = [&](size_t bytes) -> void* {
    void* r = (void*)p;
    p += (bytes + 255) & ~(size_t)255;
    return r;
  };
  int*   dflag   = (int*)carve(4);
  float* conv    = (float*)carve((size_t)tot * 4);
  float* h_lin   = (float*)carve((size_t)N * 256 * 4);  // 64-wide tmp / z
  float* h_agg   = (float*)carve((size_t)N * 64 * 4);   // h after agg / final h4
  float* asrc    = (float*)carve((size_t)N * 8 * 4);
  float* adst    = (float*)carve((size_t)N * 8 * 4);
  int*   counts  = (int*)carve((size_t)N * 4);
  int*   row_ptr = (int*)carve((size_t)(N + 1) * 4);
  int*   esrc    = (int*)carve((size_t)ET * 4);
  float* fp      = (float*)carve(8 * 64 * 4);
  float* avs     = (float*)carve(256 * 4);
  float* avd     = (float*)carve(256 * 4);
  float* wz      = (float*)carve(256 * 64 * 4);

  if ((size_t)(p - (char*)d_ws) > ws_size) return;

  const float* cW1 = conv + cd.off[1],  *cas1 = conv + cd.off[2],  *cad1 = conv + cd.off[3],  *cb1 = conv + cd.off[4];
  const float* cW2 = conv + cd.off[5],  *cas2 = conv + cd.off[6],  *cad2 = conv + cd.off[7],  *cb2 = conv + cd.off[8];
  const float* cW3 = conv + cd.off[9],  *cas3 = conv + cd.off[10], *cad3 = conv + cd.off[11], *cb3 = conv + cd.off[12];
  const float* cW4 = conv + cd.off[13], *cas4 = conv + cd.off[14], *cad4 = conv + cd.off[15], *cb4 = conv + cd.off[16];
  const float* cWp = conv + cd.off[17], *cWt = conv + cd.off[18], *cWo = conv + cd.off[19], *cbo = conv + cd.off[20];
  const float* xf  = conv + cd.off[0];

  const int TB = 256;

  hipMemsetAsync(dflag, 0, 4, stream);
  int nprobe = in_sizes[0] < 4096 ? in_sizes[0] : 4096;
  detect_k<<<1, TB, 0, stream>>>((const unsigned short*)d_in[0], nprobe, dflag);
  convert_all_k<<<(tot + TB - 1) / TB, TB, 0, stream>>>(cd, conv, dflag, tot);

  int eb = (ET + TB - 1) / TB;
  hipMemsetAsync(counts, 0, (size_t)N * 4, stream);
  count_edges_k<<<eb, TB, 0, stream>>>(ei, counts, E, N);
  scan_k<<<1, 1024, 0, stream>>>(counts, row_ptr, N);
  hipMemsetAsync(counts, 0, (size_t)N * 4, stream);
  scatter_k<<<eb, TB, 0, stream>>>(ei, row_ptr, counts, esrc, E, N);

  int agg_blocks = (N * 64 + TB - 1) / TB;
  int lin_blocks = (N + 63) / 64;

  // layer 1: 16 -> 8x8
  linear_e_k<16, 64, 64, false><<<dim3(lin_blocks, 1), TB, 0, stream>>>(xf, cW1, nullptr, h_lin, N);
  alpha_k<<<(N * 8 + TB - 1) / TB, TB, 0, stream>>>(h_lin, cas1, cad1, asrc, adst, N, 8, 8);
  agg8_k<<<agg_blocks, TB, 0, stream>>>(h_lin, asrc, adst, row_ptr, esrc, cb1, h_agg, N);

  // layer 2
  linear_e_k<64, 64, 64, false><<<dim3(lin_blocks, 1), TB, 0, stream>>>(h_agg, cW2, nullptr, h_lin, N);
  alpha_k<<<(N * 8 + TB - 1) / TB, TB, 0, stream>>>(h_lin, cas2, cad2, asrc, adst, N, 8, 8);
  agg8_k<<<agg_blocks, TB, 0, stream>>>(h_lin, asrc, adst, row_ptr, esrc, cb2, h_agg, N);

  // layer 3
  linear_e_k<64, 64, 64, false><<<dim3(lin_blocks, 1), TB, 0, stream>>>(h_agg, cW3, nullptr, h_lin, N);
  alpha_k<<<(N * 8 + TB - 1) / TB, TB, 0, stream>>>(h_lin, cas3, cad3, asrc, adst, N, 8, 8);
  agg8_k<<<agg_blocks, TB, 0, stream>>>(h_lin, asrc, adst, row_ptr, esrc, cb3, h_agg, N);

  // layer 4 (algebraic, no h4): alpha from h3, gather z, then z @ Wz (+b, elu)
  av_k<<<1, 256, 0, stream>>>(cW4, cas4, cad4, avs, avd);
  alpha4_k<<<(N * 4 + TB - 1) / TB, TB, 0, stream>>>(h_agg, avs, avd, asrc, adst, N);
  wz_k<<<64, TB, 0, stream>>>(cW4, wz);
  aggz_k<<<agg_blocks, TB, 0, stream>>>(h_agg, asrc, adst, row_ptr, esrc, h_lin, N);
  linear_e_k<256, 64, 64, true><<<dim3(lin_blocks, 1), TB, 0, stream>>>(h_lin, wz, cb4, h_agg, N);

  hipMemsetAsync(fp, 0, 8 * 64 * 4, stream);
  pool_k<<<64, TB, 0, stream>>>(h_agg, fidx, flagg, fp, M);
  final_k<<<1, 512, 0, stream>>>(fp, h_agg, dec, cWp, cWt, cWo, cbo, d_out, dflag);
}

// Round 7
// 439.946 us; speedup vs baseline: 1.0990x; 1.0990x over previous
//
#include <hip/hip_runtime.h>
#include <hip/hip_bf16.h>
#include <math.h>

typedef __hip_bfloat16 bf16;

__device__ __forceinline__ float b2f(bf16 v){ return __bfloat162float(v); }
__device__ __forceinline__ float eluf(float x){ return x > 0.f ? x : __expf(x) - 1.f; }
__device__ __forceinline__ float lrelu(float x){ return x > 0.f ? x : 0.2f * x; }

// ---------------- dtype detection ----------------
// flag: 0 = bf16 inputs, 1 = fp32 inputs. (Round-2 evidence: bf16.)
__global__ void detect_k(const unsigned short* __restrict__ u16, int n, int* __restrict__ flag){
  int bad = 0;
  for (int k = threadIdx.x; k < n; k += 256){
    int ex = (u16[k] >> 7) & 0xFF;
    if (ex >= 0xC6) bad = 1;
  }
  if (__any(bad) && (threadIdx.x & 63) == 0) atomicOr(flag, 1);
}

// ---------------- unified input conversion to fp32 ----------------
struct ConvDesc {
  const void* src[21];
  int off[22];
};

__global__ void convert_all_k(ConvDesc d, float* __restrict__ out,
                              const int* __restrict__ flag, int total){
  int i = blockIdx.x * blockDim.x + threadIdx.x;
  if (i >= total) return;
  int a = 0;
  while (i >= d.off[a + 1]) ++a;
  int j = i - d.off[a];
  float v;
  if (*flag) v = ((const float*)d.src[a])[j];
  else       v = b2f(((const bf16*)d.src[a])[j]);
  out[i] = v;
}

// ---------------- CSR build (dst identical for all 4 layers) ----------------

__global__ void count_edges_k(const int* __restrict__ ei, int* __restrict__ counts, int E, int n){
  int e = blockIdx.x * blockDim.x + threadIdx.x;
  if (e >= E + n) return;
  int d = (e < E) ? ei[E + e] : (e - E);
  atomicAdd(&counts[d], 1);
}

__global__ void scan_k(const int* __restrict__ counts, int* __restrict__ row_ptr, int n){
  __shared__ int psum[1024];
  int t = threadIdx.x;
  int chunk = (n + 1023) >> 10;
  int beg = t * chunk;
  int end = beg + chunk; if (end > n) end = n;
  int s = 0;
  for (int i = beg; i < end; ++i) s += counts[i];
  psum[t] = s;
  __syncthreads();
  for (int off = 1; off < 1024; off <<= 1){
    int v = (t >= off) ? psum[t - off] : 0;
    __syncthreads();
    psum[t] += v;
    __syncthreads();
  }
  int run = psum[t] - s;
  for (int i = beg; i < end; ++i){ row_ptr[i] = run; run += counts[i]; }
  if (beg < n && end == n) row_ptr[n] = run;
}

__global__ void scatter_k(const int* __restrict__ ei, const int* __restrict__ row_ptr,
                          int* __restrict__ fill, int* __restrict__ esrc, int E, int n){
  int e = blockIdx.x * blockDim.x + threadIdx.x;
  if (e >= E + n) return;
  int s, d;
  if (e < E){ s = ei[e]; d = ei[E + e]; } else { s = e - E; d = s; }
  int pos = row_ptr[d] + atomicAdd(&fill[d], 1);
  esrc[pos] = s;
}

// ---------------- small-tile linear: 16 nodes/block, 1250 blocks ------------
// Y[n,64] = act(X[n,K] @ W[K,64] + bias).  Thread = (node, out-quad):
// 4 register accumulators; W chunk (<=16KB) + X^T chunk (<=4.4KB) in LDS.
// ALPHA: fuse GAT attention logits (H=8,C=8) into the epilogue via shfl_xor.
// (Round-6 postmortem: 64-node tiles => 313 blocks => 1 wave/SIMD, latency-
//  bound 55us each. 1250 blocks => ~20 waves/CU hides LDS latency.)
template<int K, bool ELU, bool ALPHA>
__global__ void linear_s_k(const float* __restrict__ X, const float* __restrict__ W,
                           const float* __restrict__ bias,
                           const float* __restrict__ a_src, const float* __restrict__ a_dst,
                           float* __restrict__ Y, float* __restrict__ asrc,
                           float* __restrict__ adst, int n){
  constexpr int KC = (K > 64) ? 64 : K;
  __shared__ float wl[KC * 64];
  __shared__ float xt[KC][17];
  int base = blockIdx.x * 16;
  int t = threadIdx.x;
  int lane = t & 63, wv = t >> 6;
  int node = wv * 4 + (lane >> 4);   // 0..15
  int jj = lane & 15;                // out-quad
  float ax = 0.f, ay = 0.f, az = 0.f, aw = 0.f;
  for (int kb = 0; kb < K; kb += KC){
    if (kb) __syncthreads();
    for (int q = t; q < KC * 16; q += 256)
      ((float4*)wl)[q] = ((const float4*)(W + (size_t)(kb + (q >> 4)) * 64))[q & 15];
    for (int q = t; q < 16 * (KC / 4); q += 256){
      int nd = q / (KC / 4);
      int k4 = q - nd * (KC / 4);
      float4 v = make_float4(0.f, 0.f, 0.f, 0.f);
      if (base + nd < n) v = *(const float4*)(X + (size_t)(base + nd) * K + kb + k4 * 4);
      xt[k4 * 4 + 0][nd] = v.x;
      xt[k4 * 4 + 1][nd] = v.y;
      xt[k4 * 4 + 2][nd] = v.z;
      xt[k4 * 4 + 3][nd] = v.w;
    }
    __syncthreads();
#pragma unroll 8
    for (int k = 0; k < KC; ++k){
      float xv = xt[k][node];
      float4 w = ((const float4*)wl)[k * 16 + jj];
      ax += xv * w.x; ay += xv * w.y; az += xv * w.z; aw += xv * w.w;
    }
  }
  int gn = base + node;
  if (ELU){
    if (gn < n){
      float4 b = ((const float4*)bias)[jj];
      ((float4*)(Y + (size_t)gn * 64))[jj] =
        make_float4(eluf(ax + b.x), eluf(ay + b.y), eluf(az + b.z), eluf(aw + b.w));
    }
  } else {
    if (gn < n)
      ((float4*)(Y + (size_t)gn * 64))[jj] = make_float4(ax, ay, az, aw);
  }
  if (ALPHA){
    // channels 4jj..4jj+3 all in head h = jj>>1 (C=8). Partial dots + pair-sum.
    float4 as = *(const float4*)(a_src + 4 * jj);
    float4 ad = *(const float4*)(a_dst + 4 * jj);
    float s1 = ax * as.x + ay * as.y + az * as.z + aw * as.w;
    float s2 = ax * ad.x + ay * ad.y + az * ad.z + aw * ad.w;
    s1 += __shfl_xor(s1, 1);
    s2 += __shfl_xor(s2, 1);
    if (gn < n){
      int h = jj >> 1;
      if ((jj & 1) == 0) asrc[gn * 8 + h] = s1;
      else               adst[gn * 8 + h] = s2;
    }
  }
}

// ---------------- layer-4 algebraic restructure ----------------
// av[h*64+k] = sum_c W4[k, h*64+c] * a4[h,c]   (fold W4 into attention vecs)
__global__ void av_k(const float* __restrict__ W4, const float* __restrict__ as4,
                     const float* __restrict__ ad4, float* __restrict__ avs,
                     float* __restrict__ avd){
  int t = threadIdx.x;            // t = h*64+k
  int h = t >> 6, k = t & 63;
  const float* wr = W4 + (size_t)k * 256 + h * 64;
  const float* sr = as4 + h * 64;
  const float* dr = ad4 + h * 64;
  float s1 = 0.f, s2 = 0.f;
  for (int c = 0; c < 64; ++c){ float w = wr[c]; s1 += w * sr[c]; s2 += w * dr[c]; }
  avs[t] = s1;
  avd[t] = s2;
}

// alpha4 from h3 directly: asrc[n*4+h] = h3[n,:] . avs[h,:]
__global__ void alpha4_k(const float* __restrict__ h3, const float* __restrict__ avs,
                         const float* __restrict__ avd, float* __restrict__ asrc,
                         float* __restrict__ adst, int n){
  int i = blockIdx.x * blockDim.x + threadIdx.x;
  if (i >= n * 4) return;
  int node = i >> 2, head = i & 3;
  const float4* hp = (const float4*)(h3 + (size_t)node * 64);
  const float4* sp = (const float4*)(avs + head * 64);
  const float4* dp = (const float4*)(avd + head * 64);
  float s1 = 0.f, s2 = 0.f;
#pragma unroll 4
  for (int q = 0; q < 16; ++q){
    float4 v = hp[q], a = sp[q], d = dp[q];
    s1 += v.x * a.x + v.y * a.y + v.z * a.z + v.w * a.w;
    s2 += v.x * d.x + v.y * d.y + v.z * d.z + v.w * d.w;
  }
  asrc[i] = s1;
  adst[i] = s2;
}

// Wz[h*64+k][c] = 0.25 * W4[k][h*64+c]  (head-mean folded; 256x64)
__global__ void wz_k(const float* __restrict__ W4, float* __restrict__ Wz){
  int t = blockIdx.x * 256 + threadIdx.x;   // t < 16384
  int r = t >> 6, c = t & 63;
  int h = r >> 6, k = r & 63;
  Wz[(size_t)r * 64 + c] = 0.25f * W4[(size_t)k * 256 + h * 64 + c];
}

// Layer-4 gather: z[n, h*64+c] = sum_e w_e h3[s_e, c] / sw_h.
// One wave per node; weights computed edge-batched (16 edges x 4 heads / exp).
__global__ void aggz_k(const float* __restrict__ h3, const float* __restrict__ asrc,
                       const float* __restrict__ adst, const int* __restrict__ row_ptr,
                       const int* __restrict__ esrc, float* __restrict__ z, int n){
  int node = (blockIdx.x * blockDim.x + threadIdx.x) >> 6;
  if (node >= n) return;
  int lane = threadIdx.x & 63;
  int h = lane >> 4, j = lane & 15;
  int beg = row_ptr[node], end = row_ptr[node + 1];
  float4 adv = *(const float4*)(adst + (size_t)node * 4);
  float adh = h == 0 ? adv.x : h == 1 ? adv.y : h == 2 ? adv.z : adv.w;
  float m = -INFINITY;
  for (int p = beg + j; p < end; p += 16)
    m = fmaxf(m, lrelu(asrc[esrc[p] * 4 + h] + adh));
  m = fmaxf(m, __shfl_xor(m, 1));
  m = fmaxf(m, __shfl_xor(m, 2));
  m = fmaxf(m, __shfl_xor(m, 4));
  m = fmaxf(m, __shfl_xor(m, 8));
  float acc0 = 0.f, acc1 = 0.f, acc2 = 0.f, acc3 = 0.f, swp = 0.f;
  for (int b0 = beg; b0 < end; b0 += 16){
    int p = b0 + j;
    float w = 0.f; int s = 0;
    if (p < end){ s = esrc[p]; w = __expf(lrelu(asrc[s * 4 + h] + adh) - m); }
    swp += w;
    int cnt = end - b0; if (cnt > 16) cnt = 16;
    for (int i = 0; i < cnt; ++i){
      int   si = __shfl(s, i);
      float hv = h3[(size_t)si * 64 + lane];
      float w0 = __shfl(w, i);
      float w1 = __shfl(w, 16 + i);
      float w2 = __shfl(w, 32 + i);
      float w3 = __shfl(w, 48 + i);
      acc0 += hv * w0; acc1 += hv * w1; acc2 += hv * w2; acc3 += hv * w3;
    }
  }
  swp += __shfl_xor(swp, 1);
  swp += __shfl_xor(swp, 2);
  swp += __shfl_xor(swp, 4);
  swp += __shfl_xor(swp, 8);
  float sw0 = __shfl(swp, 0), sw1 = __shfl(swp, 16);
  float sw2 = __shfl(swp, 32), sw3 = __shfl(swp, 48);
  size_t zb = (size_t)node * 256;
  z[zb + lane]        = acc0 / sw0;
  z[zb + 64 + lane]   = acc1 / sw1;
  z[zb + 128 + lane]  = acc2 / sw2;
  z[zb + 192 + lane]  = acc3 / sw3;
}

// Layers 1-3: H=8, C=8. One wave per dst node; lane = head*8+j = channel.
__global__ void agg8_k(const float* __restrict__ hlin, const float* __restrict__ asrc,
                       const float* __restrict__ adst, const int* __restrict__ row_ptr,
                       const int* __restrict__ esrc, const float* __restrict__ bias,
                       float* __restrict__ hout, int n){
  int node = (blockIdx.x * blockDim.x + threadIdx.x) >> 6;
  if (node >= n) return;
  int lane = threadIdx.x & 63;
  int head = lane >> 3;
  int j = lane & 7;
  int beg = row_ptr[node], end = row_ptr[node + 1];
  float ad = adst[node * 8 + head];
  float m = -INFINITY;
  for (int p = beg + j; p < end; p += 8){
    int s = esrc[p];
    m = fmaxf(m, lrelu(asrc[s * 8 + head] + ad));
  }
  m = fmaxf(m, __shfl_xor(m, 1));
  m = fmaxf(m, __shfl_xor(m, 2));
  m = fmaxf(m, __shfl_xor(m, 4));
  float acc = 0.f, sw = 0.f;
  for (int p = beg; p < end; ++p){
    int s = esrc[p];
    float w = __expf(lrelu(asrc[s * 8 + head] + ad) - m);
    sw += w;
    acc += hlin[(size_t)s * 64 + lane] * w;
  }
  float o = acc / sw + bias[lane];
  hout[(size_t)node * 64 + lane] = eluf(o);
}

// ---------------- pooling + head ----------------

__global__ void pool_k(const float* __restrict__ h, const int* __restrict__ fidx,
                       const int* __restrict__ flag_arr, float* __restrict__ fp, int m){
  __shared__ float acc[512];
  for (int t = threadIdx.x; t < 512; t += blockDim.x) acc[t] = 0.f;
  __syncthreads();
  int lane = threadIdx.x & 63;
  int wave = (blockIdx.x * blockDim.x + threadIdx.x) >> 6;
  int nwaves = (gridDim.x * blockDim.x) >> 6;
  for (int i = wave; i < m; i += nwaves){
    int g = flag_arr[i];
    int node = fidx[i];
    atomicAdd(&acc[g * 64 + lane], h[(size_t)node * 64 + lane]);
  }
  __syncthreads();
  for (int t = threadIdx.x; t < 512; t += blockDim.x)
    atomicAdd(&fp[t], acc[t]);
}

__global__ void final_k(const float* __restrict__ fp, const float* __restrict__ h,
                        const int* __restrict__ dec,
                        const float* __restrict__ Wp, const float* __restrict__ Wt,
                        const float* __restrict__ Wo, const float* __restrict__ bo,
                        void* __restrict__ out, const int* __restrict__ dflag){
  int g = threadIdx.x >> 6;
  int j = threadIdx.x & 63;
  const float* fr = fp + g * 64;
  const float* tr = h + (size_t)dec[g] * 64;
  float a = 0.f, b = 0.f;
  for (int k = 0; k < 64; ++k){
    a += fr[k] * Wp[k * 64 + j];
    b += tr[k] * Wt[k * 64 + j];
  }
  float v = eluf(a) * Wo[j] + eluf(b) * Wo[64 + j];
  for (int off = 32; off > 0; off >>= 1) v += __shfl_down(v, off);
  if (j == 0){
    float r = v + bo[0];
    if (*dflag) ((float*)out)[g] = r;
    else        ((bf16*)out)[g] = __float2bfloat16(r);
  }
}

// ---------------- launch ----------------

extern "C" void kernel_launch(void* const* d_in, const int* in_sizes, int n_in,
                              void* d_out, int out_size, void* d_ws, size_t ws_size,
                              hipStream_t stream) {
  const int*  ei    = (const int*)d_in[1];
  const int*  fidx  = (const int*)d_in[2];
  const int*  flagg = (const int*)d_in[3];
  const int*  dec   = (const int*)d_in[4];

  const int N = in_sizes[0] / 16;   // 20000
  const int E = in_sizes[1] / 2;    // 320000
  const int M = in_sizes[2];        // 8000
  const int ET = E + N;

  const int fidxs[21] = {0,5,6,7,8,9,10,11,12,13,14,15,16,17,18,19,20,21,22,23,24};
  ConvDesc cd;
  int tot = 0;
  for (int k = 0; k < 21; ++k){
    cd.src[k] = d_in[fidxs[k]];
    cd.off[k] = tot;
    tot += in_sizes[fidxs[k]];
  }
  cd.off[21] = tot;

  char* p = (char*)d_ws;
  auto carve = [&](size_t bytes) -> void* {
    void* r = (void*)p;
    p += (bytes + 255) & ~(size_t)255;
    return r;
  };
  int*   dflag   = (int*)carve(4);
  float* conv    = (float*)carve((size_t)tot * 4);
  float* h_lin   = (float*)carve((size_t)N * 256 * 4);  // 64-wide tmp / z
  float* h_agg   = (float*)carve((size_t)N * 64 * 4);   // h after agg / final h4
  float* asrc    = (float*)carve((size_t)N * 8 * 4);
  float* adst    = (float*)carve((size_t)N * 8 * 4);
  int*   counts  = (int*)carve((size_t)N * 4);
  int*   row_ptr = (int*)carve((size_t)(N + 1) * 4);
  int*   esrc    = (int*)carve((size_t)ET * 4);
  float* fp      = (float*)carve(8 * 64 * 4);
  float* avs     = (float*)carve(256 * 4);
  float* avd     = (float*)carve(256 * 4);
  float* wz      = (float*)carve(256 * 64 * 4);

  if ((size_t)(p - (char*)d_ws) > ws_size) return;

  const float* cW1 = conv + cd.off[1],  *cas1 = conv + cd.off[2],  *cad1 = conv + cd.off[3],  *cb1 = conv + cd.off[4];
  const float* cW2 = conv + cd.off[5],  *cas2 = conv + cd.off[6],  *cad2 = conv + cd.off[7],  *cb2 = conv + cd.off[8];
  const float* cW3 = conv + cd.off[9],  *cas3 = conv + cd.off[10], *cad3 = conv + cd.off[11], *cb3 = conv + cd.off[12];
  const float* cW4 = conv + cd.off[13], *cas4 = conv + cd.off[14], *cad4 = conv + cd.off[15], *cb4 = conv + cd.off[16];
  const float* cWp = conv + cd.off[17], *cWt = conv + cd.off[18], *cWo = conv + cd.off[19], *cbo = conv + cd.off[20];
  const float* xf  = conv + cd.off[0];

  const int TB = 256;

  hipMemsetAsync(dflag, 0, 4, stream);
  int nprobe = in_sizes[0] < 4096 ? in_sizes[0] : 4096;
  detect_k<<<1, TB, 0, stream>>>((const unsigned short*)d_in[0], nprobe, dflag);
  convert_all_k<<<(tot + TB - 1) / TB, TB, 0, stream>>>(cd, conv, dflag, tot);

  int eb = (ET + TB - 1) / TB;
  hipMemsetAsync(counts, 0, (size_t)N * 4, stream);
  count_edges_k<<<eb, TB, 0, stream>>>(ei, counts, E, N);
  scan_k<<<1, 1024, 0, stream>>>(counts, row_ptr, N);
  hipMemsetAsync(counts, 0, (size_t)N * 4, stream);
  scatter_k<<<eb, TB, 0, stream>>>(ei, row_ptr, counts, esrc, E, N);

  int agg_blocks = (N * 64 + TB - 1) / TB;
  int ls_blocks  = (N + 15) / 16;   // 1250

  // layer 1: 16 -> 8x8 (linear + fused alpha)
  linear_s_k<16, false, true><<<ls_blocks, TB, 0, stream>>>(xf, cW1, nullptr, cas1, cad1, h_lin, asrc, adst, N);
  agg8_k<<<agg_blocks, TB, 0, stream>>>(h_lin, asrc, adst, row_ptr, esrc, cb1, h_agg, N);

  // layer 2
  linear_s_k<64, false, true><<<ls_blocks, TB, 0, stream>>>(h_agg, cW2, nullptr, cas2, cad2, h_lin, asrc, adst, N);
  agg8_k<<<agg_blocks, TB, 0, stream>>>(h_lin, asrc, adst, row_ptr, esrc, cb2, h_agg, N);

  // layer 3
  linear_s_k<64, false, true><<<ls_blocks, TB, 0, stream>>>(h_agg, cW3, nullptr, cas3, cad3, h_lin, asrc, adst, N);
  agg8_k<<<agg_blocks, TB, 0, stream>>>(h_lin, asrc, adst, row_ptr, esrc, cb3, h_agg, N);

  // layer 4 (algebraic, no h4): alpha from h3, gather z, then z @ Wz (+b, elu)
  av_k<<<1, 256, 0, stream>>>(cW4, cas4, cad4, avs, avd);
  alpha4_k<<<(N * 4 + TB - 1) / TB, TB, 0, stream>>>(h_agg, avs, avd, asrc, adst, N);
  wz_k<<<64, TB, 0, stream>>>(cW4, wz);
  aggz_k<<<agg_blocks, TB, 0, stream>>>(h_agg, asrc, adst, row_ptr, esrc, h_lin, N);
  linear_s_k<256, true, false><<<ls_blocks, TB, 0, stream>>>(h_lin, wz, cb4, nullptr, nullptr, h_agg, nullptr, nullptr, N);

  hipMemsetAsync(fp, 0, 8 * 64 * 4, stream);
  pool_k<<<64, TB, 0, stream>>>(h_agg, fidx, flagg, fp, M);
  final_k<<<1, 512, 0, stream>>>(fp, h_agg, dec, cWp, cWt, cWo, cbo, d_out, dflag);
}

// Round 8
// 381.247 us; speedup vs baseline: 1.2682x; 1.1540x over previous
//
#include <hip/hip_runtime.h>
#include <hip/hip_bf16.h>
#include <math.h>

typedef __hip_bfloat16 bf16;

__device__ __forceinline__ float b2f(bf16 v){ return __bfloat162float(v); }
__device__ __forceinline__ float eluf(float x){ return x > 0.f ? x : __expf(x) - 1.f; }
__device__ __forceinline__ float lrelu(float x){ return x > 0.f ? x : 0.2f * x; }

// ---------------- dtype detection ----------------
// flag: 0 = bf16 inputs, 1 = fp32 inputs. (Round-2 evidence: bf16.)
__global__ void detect_k(const unsigned short* __restrict__ u16, int n, int* __restrict__ flag){
  int bad = 0;
  for (int k = threadIdx.x; k < n; k += 256){
    int ex = (u16[k] >> 7) & 0xFF;
    if (ex >= 0xC6) bad = 1;
  }
  if (__any(bad) && (threadIdx.x & 63) == 0) atomicOr(flag, 1);
}

// ---------------- unified input conversion to fp32 ----------------
struct ConvDesc {
  const void* src[21];
  int off[22];
};

__global__ void convert_all_k(ConvDesc d, float* __restrict__ out,
                              const int* __restrict__ flag, int total){
  int i = blockIdx.x * blockDim.x + threadIdx.x;
  if (i >= total) return;
  int a = 0;
  while (i >= d.off[a + 1]) ++a;
  int j = i - d.off[a];
  float v;
  if (*flag) v = ((const float*)d.src[a])[j];
  else       v = b2f(((const bf16*)d.src[a])[j]);
  out[i] = v;
}

// ---------------- CSR build (dst identical for all 4 layers) ----------------

__global__ void count_edges_k(const int* __restrict__ ei, int* __restrict__ counts, int E, int n){
  int e = blockIdx.x * blockDim.x + threadIdx.x;
  if (e >= E + n) return;
  int d = (e < E) ? ei[E + e] : (e - E);
  atomicAdd(&counts[d], 1);
}

__global__ void scan_k(const int* __restrict__ counts, int* __restrict__ row_ptr, int n){
  __shared__ int psum[1024];
  int t = threadIdx.x;
  int chunk = (n + 1023) >> 10;
  int beg = t * chunk;
  int end = beg + chunk; if (end > n) end = n;
  int s = 0;
  for (int i = beg; i < end; ++i) s += counts[i];
  psum[t] = s;
  __syncthreads();
  for (int off = 1; off < 1024; off <<= 1){
    int v = (t >= off) ? psum[t - off] : 0;
    __syncthreads();
    psum[t] += v;
    __syncthreads();
  }
  int run = psum[t] - s;
  for (int i = beg; i < end; ++i){ row_ptr[i] = run; run += counts[i]; }
  if (beg < n && end == n) row_ptr[n] = run;
}

__global__ void scatter_k(const int* __restrict__ ei, const int* __restrict__ row_ptr,
                          int* __restrict__ fill, int* __restrict__ esrc, int E, int n){
  int e = blockIdx.x * blockDim.x + threadIdx.x;
  if (e >= E + n) return;
  int s, d;
  if (e < E){ s = ei[e]; d = ei[E + e]; } else { s = e - E; d = s; }
  int pos = row_ptr[d] + atomicAdd(&fill[d], 1);
  esrc[pos] = s;
}

// ---------------- small-tile linear: 16 nodes/block, 1250 blocks ------------
template<int K, bool ELU, bool ALPHA>
__global__ void linear_s_k(const float* __restrict__ X, const float* __restrict__ W,
                           const float* __restrict__ bias,
                           const float* __restrict__ a_src, const float* __restrict__ a_dst,
                           float* __restrict__ Y, float* __restrict__ asrc,
                           float* __restrict__ adst, int n){
  constexpr int KC = (K > 64) ? 64 : K;
  __shared__ float wl[KC * 64];
  __shared__ float xt[KC][17];
  int base = blockIdx.x * 16;
  int t = threadIdx.x;
  int lane = t & 63, wv = t >> 6;
  int node = wv * 4 + (lane >> 4);   // 0..15
  int jj = lane & 15;                // out-quad
  float ax = 0.f, ay = 0.f, az = 0.f, aw = 0.f;
  for (int kb = 0; kb < K; kb += KC){
    if (kb) __syncthreads();
    for (int q = t; q < KC * 16; q += 256)
      ((float4*)wl)[q] = ((const float4*)(W + (size_t)(kb + (q >> 4)) * 64))[q & 15];
    for (int q = t; q < 16 * (KC / 4); q += 256){
      int nd = q / (KC / 4);
      int k4 = q - nd * (KC / 4);
      float4 v = make_float4(0.f, 0.f, 0.f, 0.f);
      if (base + nd < n) v = *(const float4*)(X + (size_t)(base + nd) * K + kb + k4 * 4);
      xt[k4 * 4 + 0][nd] = v.x;
      xt[k4 * 4 + 1][nd] = v.y;
      xt[k4 * 4 + 2][nd] = v.z;
      xt[k4 * 4 + 3][nd] = v.w;
    }
    __syncthreads();
#pragma unroll 8
    for (int k = 0; k < KC; ++k){
      float xv = xt[k][node];
      float4 w = ((const float4*)wl)[k * 16 + jj];
      ax += xv * w.x; ay += xv * w.y; az += xv * w.z; aw += xv * w.w;
    }
  }
  int gn = base + node;
  if (ELU){
    if (gn < n){
      float4 b = ((const float4*)bias)[jj];
      ((float4*)(Y + (size_t)gn * 64))[jj] =
        make_float4(eluf(ax + b.x), eluf(ay + b.y), eluf(az + b.z), eluf(aw + b.w));
    }
  } else {
    if (gn < n)
      ((float4*)(Y + (size_t)gn * 64))[jj] = make_float4(ax, ay, az, aw);
  }
  if (ALPHA){
    float4 as = *(const float4*)(a_src + 4 * jj);
    float4 ad = *(const float4*)(a_dst + 4 * jj);
    float s1 = ax * as.x + ay * as.y + az * as.z + aw * as.w;
    float s2 = ax * ad.x + ay * ad.y + az * ad.z + aw * ad.w;
    s1 += __shfl_xor(s1, 1);
    s2 += __shfl_xor(s2, 1);
    if (gn < n){
      int h = jj >> 1;
      if ((jj & 1) == 0) asrc[gn * 8 + h] = s1;
      else               adst[gn * 8 + h] = s2;
    }
  }
}

// ---------------- layer-4 algebraic restructure ----------------
__global__ void av_k(const float* __restrict__ W4, const float* __restrict__ as4,
                     const float* __restrict__ ad4, float* __restrict__ avs,
                     float* __restrict__ avd){
  int t = threadIdx.x;            // t = h*64+k
  int h = t >> 6, k = t & 63;
  const float* wr = W4 + (size_t)k * 256 + h * 64;
  const float* sr = as4 + h * 64;
  const float* dr = ad4 + h * 64;
  float s1 = 0.f, s2 = 0.f;
  for (int c = 0; c < 64; ++c){ float w = wr[c]; s1 += w * sr[c]; s2 += w * dr[c]; }
  avs[t] = s1;
  avd[t] = s2;
}

__global__ void alpha4_k(const float* __restrict__ h3, const float* __restrict__ avs,
                         const float* __restrict__ avd, float* __restrict__ asrc,
                         float* __restrict__ adst, int n){
  int i = blockIdx.x * blockDim.x + threadIdx.x;
  if (i >= n * 4) return;
  int node = i >> 2, head = i & 3;
  const float4* hp = (const float4*)(h3 + (size_t)node * 64);
  const float4* sp = (const float4*)(avs + head * 64);
  const float4* dp = (const float4*)(avd + head * 64);
  float s1 = 0.f, s2 = 0.f;
#pragma unroll 4
  for (int q = 0; q < 16; ++q){
    float4 v = hp[q], a = sp[q], d = dp[q];
    s1 += v.x * a.x + v.y * a.y + v.z * a.z + v.w * a.w;
    s2 += v.x * d.x + v.y * d.y + v.z * d.z + v.w * d.w;
  }
  asrc[i] = s1;
  adst[i] = s2;
}

// Wz[h*64+k][c] = 0.25 * W4[k][h*64+c]  (head-mean folded; 256x64)
__global__ void wz_k(const float* __restrict__ W4, float* __restrict__ Wz){
  int t = blockIdx.x * 256 + threadIdx.x;   // t < 16384
  int r = t >> 6, c = t & 63;
  int h = r >> 6, k = r & 63;
  Wz[(size_t)r * 64 + c] = 0.25f * W4[(size_t)k * 256 + h * 64 + c];
}

// Layer-4 gather: z[n, h*64+c] = sum_e w_e h3[s_e, c] / sw_h.
// Edge-batched weights; full-batch path unrolled for load batching.
__global__ void aggz_k(const float* __restrict__ h3, const float* __restrict__ asrc,
                       const float* __restrict__ adst, const int* __restrict__ row_ptr,
                       const int* __restrict__ esrc, float* __restrict__ z, int n){
  int node = (blockIdx.x * blockDim.x + threadIdx.x) >> 6;
  if (node >= n) return;
  int lane = threadIdx.x & 63;
  int h = lane >> 4, j = lane & 15;
  int beg = row_ptr[node], end = row_ptr[node + 1];
  float4 adv = *(const float4*)(adst + (size_t)node * 4);
  float adh = h == 0 ? adv.x : h == 1 ? adv.y : h == 2 ? adv.z : adv.w;
  float m = -INFINITY;
  for (int p = beg + j; p < end; p += 16)
    m = fmaxf(m, lrelu(asrc[esrc[p] * 4 + h] + adh));
  m = fmaxf(m, __shfl_xor(m, 1));
  m = fmaxf(m, __shfl_xor(m, 2));
  m = fmaxf(m, __shfl_xor(m, 4));
  m = fmaxf(m, __shfl_xor(m, 8));
  float acc0 = 0.f, acc1 = 0.f, acc2 = 0.f, acc3 = 0.f, swp = 0.f;
  for (int b0 = beg; b0 < end; b0 += 16){
    int p = b0 + j;
    float w = 0.f; int s = 0;
    if (p < end){ s = esrc[p]; w = __expf(lrelu(asrc[s * 4 + h] + adh) - m); }
    swp += w;
    int cnt = end - b0; if (cnt > 16) cnt = 16;
    if (cnt == 16){
#pragma unroll
      for (int i = 0; i < 16; ++i){
        int   si = __shfl(s, i);
        float hv = h3[(size_t)si * 64 + lane];
        float w0 = __shfl(w, i);
        float w1 = __shfl(w, 16 + i);
        float w2 = __shfl(w, 32 + i);
        float w3 = __shfl(w, 48 + i);
        acc0 += hv * w0; acc1 += hv * w1; acc2 += hv * w2; acc3 += hv * w3;
      }
    } else {
      for (int i = 0; i < cnt; ++i){
        int   si = __shfl(s, i);
        float hv = h3[(size_t)si * 64 + lane];
        float w0 = __shfl(w, i);
        float w1 = __shfl(w, 16 + i);
        float w2 = __shfl(w, 32 + i);
        float w3 = __shfl(w, 48 + i);
        acc0 += hv * w0; acc1 += hv * w1; acc2 += hv * w2; acc3 += hv * w3;
      }
    }
  }
  swp += __shfl_xor(swp, 1);
  swp += __shfl_xor(swp, 2);
  swp += __shfl_xor(swp, 4);
  swp += __shfl_xor(swp, 8);
  float sw0 = __shfl(swp, 0), sw1 = __shfl(swp, 16);
  float sw2 = __shfl(swp, 32), sw3 = __shfl(swp, 48);
  size_t zb = (size_t)node * 256;
  z[zb + lane]        = acc0 / sw0;
  z[zb + 64 + lane]   = acc1 / sw1;
  z[zb + 128 + lane]  = acc2 / sw2;
  z[zb + 192 + lane]  = acc3 / sw3;
}

// Layers 1-3: H=8, C=8. EDGE-BATCHED rewrite (round-7 postmortem: serial
// per-edge chain was latency-bound at 44us; aggz's batched loop on the same
// gather volume was faster).  lane = h*8+j: 8 edges x 8 heads per exp batch,
// then 8 INDEPENDENT h-row loads per batch with weights via shfl.
__global__ void agg8_k(const float* __restrict__ hlin, const float* __restrict__ asrc,
                       const float* __restrict__ adst, const int* __restrict__ row_ptr,
                       const int* __restrict__ esrc, const float* __restrict__ bias,
                       float* __restrict__ hout, int n){
  int node = (blockIdx.x * blockDim.x + threadIdx.x) >> 6;
  if (node >= n) return;
  int lane = threadIdx.x & 63;
  int h = lane >> 3;
  int j = lane & 7;
  int beg = row_ptr[node], end = row_ptr[node + 1];
  float ad = adst[node * 8 + h];
  float m = -INFINITY;
  for (int p = beg + j; p < end; p += 8)
    m = fmaxf(m, lrelu(asrc[esrc[p] * 8 + h] + ad));
  m = fmaxf(m, __shfl_xor(m, 1));
  m = fmaxf(m, __shfl_xor(m, 2));
  m = fmaxf(m, __shfl_xor(m, 4));   // m_h in all lanes of head group h
  float acc = 0.f, swp = 0.f;
  int hb = lane & 56;               // h*8
  for (int b0 = beg; b0 < end; b0 += 8){
    int p = b0 + j;
    float w = 0.f; int s = 0;
    if (p < end){ s = esrc[p]; w = __expf(lrelu(asrc[s * 8 + h] + ad) - m); }
    swp += w;
    int cnt = end - b0; if (cnt > 8) cnt = 8;
    if (cnt == 8){
#pragma unroll
      for (int i = 0; i < 8; ++i){
        int   si = __shfl(s, i);                       // lane i (h=0 group) has edge i
        float hv = hlin[(size_t)si * 64 + lane];
        float wi = __shfl(w, hb + i);                  // weight for (edge i, my head)
        acc += hv * wi;
      }
    } else {
      for (int i = 0; i < cnt; ++i){
        int   si = __shfl(s, i);
        float hv = hlin[(size_t)si * 64 + lane];
        float wi = __shfl(w, hb + i);
        acc += hv * wi;
      }
    }
  }
  swp += __shfl_xor(swp, 1);
  swp += __shfl_xor(swp, 2);
  swp += __shfl_xor(swp, 4);        // sw_h in all lanes of head group h
  float o = acc / swp + bias[lane];
  hout[(size_t)node * 64 + lane] = eluf(o);
}

// ---------------- pooling + head ----------------

__global__ void pool_k(const float* __restrict__ h, const int* __restrict__ fidx,
                       const int* __restrict__ flag_arr, float* __restrict__ fp, int m){
  __shared__ float acc[512];
  for (int t = threadIdx.x; t < 512; t += blockDim.x) acc[t] = 0.f;
  __syncthreads();
  int lane = threadIdx.x & 63;
  int wave = (blockIdx.x * blockDim.x + threadIdx.x) >> 6;
  int nwaves = (gridDim.x * blockDim.x) >> 6;
  for (int i = wave; i < m; i += nwaves){
    int g = flag_arr[i];
    int node = fidx[i];
    atomicAdd(&acc[g * 64 + lane], h[(size_t)node * 64 + lane]);
  }
  __syncthreads();
  for (int t = threadIdx.x; t < 512; t += blockDim.x)
    atomicAdd(&fp[t], acc[t]);
}

__global__ void final_k(const float* __restrict__ fp, const float* __restrict__ h,
                        const int* __restrict__ dec,
                        const float* __restrict__ Wp, const float* __restrict__ Wt,
                        const float* __restrict__ Wo, const float* __restrict__ bo,
                        void* __restrict__ out, const int* __restrict__ dflag){
  int g = threadIdx.x >> 6;
  int j = threadIdx.x & 63;
  const float* fr = fp + g * 64;
  const float* tr = h + (size_t)dec[g] * 64;
  float a = 0.f, b = 0.f;
  for (int k = 0; k < 64; ++k){
    a += fr[k] * Wp[k * 64 + j];
    b += tr[k] * Wt[k * 64 + j];
  }
  float v = eluf(a) * Wo[j] + eluf(b) * Wo[64 + j];
  for (int off = 32; off > 0; off >>= 1) v += __shfl_down(v, off);
  if (j == 0){
    float r = v + bo[0];
    if (*dflag) ((float*)out)[g] = r;
    else        ((bf16*)out)[g] = __float2bfloat16(r);
  }
}

// ---------------- launch ----------------

extern "C" void kernel_launch(void* const* d_in, const int* in_sizes, int n_in,
                              void* d_out, int out_size, void* d_ws, size_t ws_size,
                              hipStream_t stream) {
  const int*  ei    = (const int*)d_in[1];
  const int*  fidx  = (const int*)d_in[2];
  const int*  flagg = (const int*)d_in[3];
  const int*  dec   = (const int*)d_in[4];

  const int N = in_sizes[0] / 16;   // 20000
  const int E = in_sizes[1] / 2;    // 320000
  const int M = in_sizes[2];        // 8000
  const int ET = E + N;

  const int fidxs[21] = {0,5,6,7,8,9,10,11,12,13,14,15,16,17,18,19,20,21,22,23,24};
  ConvDesc cd;
  int tot = 0;
  for (int k = 0; k < 21; ++k){
    cd.src[k] = d_in[fidxs[k]];
    cd.off[k] = tot;
    tot += in_sizes[fidxs[k]];
  }
  cd.off[21] = tot;

  char* p = (char*)d_ws;
  auto carve = [&](size_t bytes) -> void* {
    void* r = (void*)p;
    p += (bytes + 255) & ~(size_t)255;
    return r;
  };
  int*   dflag   = (int*)carve(4);
  float* conv    = (float*)carve((size_t)tot * 4);
  float* h_lin   = (float*)carve((size_t)N * 256 * 4);  // 64-wide tmp / z
  float* h_agg   = (float*)carve((size_t)N * 64 * 4);   // h after agg / final h4
  float* asrc    = (float*)carve((size_t)N * 8 * 4);
  float* adst    = (float*)carve((size_t)N * 8 * 4);
  int*   counts  = (int*)carve((size_t)N * 4);
  int*   row_ptr = (int*)carve((size_t)(N + 1) * 4);
  int*   esrc    = (int*)carve((size_t)ET * 4);
  float* fp      = (float*)carve(8 * 64 * 4);
  float* avs     = (float*)carve(256 * 4);
  float* avd     = (float*)carve(256 * 4);
  float* wz      = (float*)carve(256 * 64 * 4);

  if ((size_t)(p - (char*)d_ws) > ws_size) return;

  const float* cW1 = conv + cd.off[1],  *cas1 = conv + cd.off[2],  *cad1 = conv + cd.off[3],  *cb1 = conv + cd.off[4];
  const float* cW2 = conv + cd.off[5],  *cas2 = conv + cd.off[6],  *cad2 = conv + cd.off[7],  *cb2 = conv + cd.off[8];
  const float* cW3 = conv + cd.off[9],  *cas3 = conv + cd.off[10], *cad3 = conv + cd.off[11], *cb3 = conv + cd.off[12];
  const float* cW4 = conv + cd.off[13], *cas4 = conv + cd.off[14], *cad4 = conv + cd.off[15], *cb4 = conv + cd.off[16];
  const float* cWp = conv + cd.off[17], *cWt = conv + cd.off[18], *cWo = conv + cd.off[19], *cbo = conv + cd.off[20];
  const float* xf  = conv + cd.off[0];

  const int TB = 256;

  hipMemsetAsync(dflag, 0, 4, stream);
  int nprobe = in_sizes[0] < 4096 ? in_sizes[0] : 4096;
  detect_k<<<1, TB, 0, stream>>>((const unsigned short*)d_in[0], nprobe, dflag);
  convert_all_k<<<(tot + TB - 1) / TB, TB, 0, stream>>>(cd, conv, dflag, tot);

  int eb = (ET + TB - 1) / TB;
  hipMemsetAsync(counts, 0, (size_t)N * 4, stream);
  count_edges_k<<<eb, TB, 0, stream>>>(ei, counts, E, N);
  scan_k<<<1, 1024, 0, stream>>>(counts, row_ptr, N);
  hipMemsetAsync(counts, 0, (size_t)N * 4, stream);
  scatter_k<<<eb, TB, 0, stream>>>(ei, row_ptr, counts, esrc, E, N);

  int agg_blocks = (N * 64 + TB - 1) / TB;
  int ls_blocks  = (N + 15) / 16;   // 1250

  // layer 1: 16 -> 8x8 (linear + fused alpha)
  linear_s_k<16, false, true><<<ls_blocks, TB, 0, stream>>>(xf, cW1, nullptr, cas1, cad1, h_lin, asrc, adst, N);
  agg8_k<<<agg_blocks, TB, 0, stream>>>(h_lin, asrc, adst, row_ptr, esrc, cb1, h_agg, N);

  // layer 2
  linear_s_k<64, false, true><<<ls_blocks, TB, 0, stream>>>(h_agg, cW2, nullptr, cas2, cad2, h_lin, asrc, adst, N);
  agg8_k<<<agg_blocks, TB, 0, stream>>>(h_lin, asrc, adst, row_ptr, esrc, cb2, h_agg, N);

  // layer 3
  linear_s_k<64, false, true><<<ls_blocks, TB, 0, stream>>>(h_agg, cW3, nullptr, cas3, cad3, h_lin, asrc, adst, N);
  agg8_k<<<agg_blocks, TB, 0, stream>>>(h_lin, asrc, adst, row_ptr, esrc, cb3, h_agg, N);

  // layer 4 (algebraic, no h4): alpha from h3, gather z, then z @ Wz (+b, elu)
  av_k<<<1, 256, 0, stream>>>(cW4, cas4, cad4, avs, avd);
  alpha4_k<<<(N * 4 + TB - 1) / TB, TB, 0, stream>>>(h_agg, avs, avd, asrc, adst, N);
  wz_k<<<64, TB, 0, stream>>>(cW4, wz);
  aggz_k<<<agg_blocks, TB, 0, stream>>>(h_agg, asrc, adst, row_ptr, esrc, h_lin, N);
  linear_s_k<256, true, false><<<ls_blocks, TB, 0, stream>>>(h_lin, wz, cb4, nullptr, nullptr, h_agg, nullptr, nullptr, N);

  hipMemsetAsync(fp, 0, 8 * 64 * 4, stream);
  pool_k<<<64, TB, 0, stream>>>(h_agg, fidx, flagg, fp, M);
  final_k<<<1, 512, 0, stream>>>(fp, h_agg, dec, cWp, cWt, cWo, cbo, d_out, dflag);
}

// Round 10
// 375.911 us; speedup vs baseline: 1.2862x; 1.0142x over previous
//
#include <hip/hip_runtime.h>
#include <hip/hip_bf16.h>
#include <math.h>

typedef __hip_bfloat16 bf16;

__device__ __forceinline__ float b2f(bf16 v){ return __bfloat162float(v); }
__device__ __forceinline__ float eluf(float x){ return x > 0.f ? x : __expf(x) - 1.f; }
__device__ __forceinline__ float lrelu(float x){ return x > 0.f ? x : 0.2f * x; }

// ---------------- dtype detection (self-contained, no pre-zero) -------------
// flag: 0 = bf16 inputs, 1 = fp32 inputs. (Round-2 evidence: bf16.)
__global__ void detect_k(const unsigned short* __restrict__ u16, int n, int* __restrict__ flag){
  __shared__ int bad_s;
  if (threadIdx.x == 0) bad_s = 0;
  __syncthreads();
  int bad = 0;
  for (int k = threadIdx.x; k < n; k += 256){
    int ex = (u16[k] >> 7) & 0xFF;
    if (ex >= 0xC6) bad = 1;
  }
  if (bad) atomicOr(&bad_s, 1);
  __syncthreads();
  if (threadIdx.x == 0) *flag = bad_s;
}

// ---------------- unified input conversion to fp32 (+ zero counts/fp) -------
struct ConvDesc {
  const void* src[21];
  int off[22];
};

__global__ void convert_all_k(ConvDesc d, float* __restrict__ out,
                              const int* __restrict__ flag, int total,
                              int* __restrict__ counts, float* __restrict__ fp, int n){
  int i = blockIdx.x * blockDim.x + threadIdx.x;
  if (i < n) counts[i] = 0;
  if (i < 512) fp[i] = 0.f;
  if (i >= total) return;
  int a = 0;
  while (i >= d.off[a + 1]) ++a;
  int j = i - d.off[a];
  float v;
  if (*flag) v = ((const float*)d.src[a])[j];
  else       v = b2f(((const bf16*)d.src[a])[j]);
  out[i] = v;
}

// ---------------- CSR build (dst identical for all 4 layers) ----------------

__global__ void count_edges_k(const int* __restrict__ ei, int* __restrict__ counts, int E, int n){
  int e = blockIdx.x * blockDim.x + threadIdx.x;
  if (e >= E + n) return;
  int d = (e < E) ? ei[E + e] : (e - E);
  atomicAdd(&counts[d], 1);
}

// prefix-scan; also re-zeroes counts so scatter can reuse it as fill[]
__global__ void scan_k(const int* __restrict__ counts_in, int* __restrict__ counts_zero,
                       int* __restrict__ row_ptr, int n){
  __shared__ int psum[1024];
  int t = threadIdx.x;
  int chunk = (n + 1023) >> 10;
  int beg = t * chunk;
  int end = beg + chunk; if (end > n) end = n;
  int s = 0;
  for (int i = beg; i < end; ++i) s += counts_in[i];
  psum[t] = s;
  __syncthreads();
  for (int off = 1; off < 1024; off <<= 1){
    int v = (t >= off) ? psum[t - off] : 0;
    __syncthreads();
    psum[t] += v;
    __syncthreads();
  }
  int run = psum[t] - s;
  for (int i = beg; i < end; ++i){
    row_ptr[i] = run; run += counts_in[i]; counts_zero[i] = 0;
  }
  if (beg < n && end == n) row_ptr[n] = run;
}

__global__ void scatter_k(const int* __restrict__ ei, const int* __restrict__ row_ptr,
                          int* __restrict__ fill, int* __restrict__ esrc, int E, int n){
  int e = blockIdx.x * blockDim.x + threadIdx.x;
  if (e >= E + n) return;
  int s, d;
  if (e < E){ s = ei[e]; d = ei[E + e]; } else { s = e - E; d = s; }
  int pos = row_ptr[d] + atomicAdd(&fill[d], 1);
  esrc[pos] = s;
}

// ---------------- small-tile linear: 16 nodes/block (layers 1 & 4) ----------
template<int K, bool ELU, bool ALPHA>
__global__ void linear_s_k(const float* __restrict__ X, const float* __restrict__ W,
                           const float* __restrict__ bias,
                           const float* __restrict__ a_src, const float* __restrict__ a_dst,
                           float* __restrict__ Y, float* __restrict__ asrc,
                           float* __restrict__ adst, int n){
  constexpr int KC = (K > 64) ? 64 : K;
  __shared__ float wl[KC * 64];
  __shared__ float xt[KC][17];
  int base = blockIdx.x * 16;
  int t = threadIdx.x;
  int lane = t & 63, wv = t >> 6;
  int node = wv * 4 + (lane >> 4);
  int jj = lane & 15;
  float ax = 0.f, ay = 0.f, az = 0.f, aw = 0.f;
  for (int kb = 0; kb < K; kb += KC){
    if (kb) __syncthreads();
    for (int q = t; q < KC * 16; q += 256)
      ((float4*)wl)[q] = ((const float4*)(W + (size_t)(kb + (q >> 4)) * 64))[q & 15];
    for (int q = t; q < 16 * (KC / 4); q += 256){
      int nd = q / (KC / 4);
      int k4 = q - nd * (KC / 4);
      float4 v = make_float4(0.f, 0.f, 0.f, 0.f);
      if (base + nd < n) v = *(const float4*)(X + (size_t)(base + nd) * K + kb + k4 * 4);
      xt[k4 * 4 + 0][nd] = v.x;
      xt[k4 * 4 + 1][nd] = v.y;
      xt[k4 * 4 + 2][nd] = v.z;
      xt[k4 * 4 + 3][nd] = v.w;
    }
    __syncthreads();
#pragma unroll 8
    for (int k = 0; k < KC; ++k){
      float xv = xt[k][node];
      float4 w = ((const float4*)wl)[k * 16 + jj];
      ax += xv * w.x; ay += xv * w.y; az += xv * w.z; aw += xv * w.w;
    }
  }
  int gn = base + node;
  if (ELU){
    if (gn < n){
      float4 b = ((const float4*)bias)[jj];
      ((float4*)(Y + (size_t)gn * 64))[jj] =
        make_float4(eluf(ax + b.x), eluf(ay + b.y), eluf(az + b.z), eluf(aw + b.w));
    }
  } else {
    if (gn < n)
      ((float4*)(Y + (size_t)gn * 64))[jj] = make_float4(ax, ay, az, aw);
  }
  if (ALPHA){
    float4 as = *(const float4*)(a_src + 4 * jj);
    float4 ad = *(const float4*)(a_dst + 4 * jj);
    float s1 = ax * as.x + ay * as.y + az * as.z + aw * as.w;
    float s2 = ax * ad.x + ay * ad.y + az * ad.z + aw * ad.w;
    s1 += __shfl_xor(s1, 1);
    s2 += __shfl_xor(s2, 1);
    if (gn < n){
      int h = jj >> 1;
      if ((jj & 1) == 0) asrc[gn * 8 + h] = s1;
      else               adst[gn * 8 + h] = s2;
    }
  }
}

// ---------------- layer-4 prep: av vectors + Wz (one kernel) ----------------
__global__ void prep4_k(const float* __restrict__ W4, const float* __restrict__ as4,
                        const float* __restrict__ ad4, float* __restrict__ avs,
                        float* __restrict__ avd, float* __restrict__ Wz){
  int g = blockIdx.x * 256 + threadIdx.x;
  int r = g >> 6, c = g & 63;
  int h = r >> 6, k = r & 63;
  Wz[(size_t)r * 64 + c] = 0.25f * W4[(size_t)k * 256 + h * 64 + c];
  if (blockIdx.x == 0){
    int t = threadIdx.x;
    int th = t >> 6, tk = t & 63;
    const float* wr = W4 + (size_t)tk * 256 + th * 64;
    const float* sr = as4 + th * 64;
    const float* dr = ad4 + th * 64;
    float s1 = 0.f, s2 = 0.f;
    for (int cc = 0; cc < 64; ++cc){ float w = wr[cc]; s1 += w * sr[cc]; s2 += w * dr[cc]; }
    avs[t] = s1;
    avd[t] = s2;
  }
}

// ---------------- fused agg8 (+ next linear + next alpha) -------------------
// RACE FIX (round-9 postmortem): alpha outputs MUST go to different buffers
// than alpha inputs — gathers read neighbor alphas while epilogues write them.
// Caller ping-pongs asrc/adst pairs (A->B->A->B).
template<int NEXT>
__global__ void agg8f_k(const float* __restrict__ hlin, const float* __restrict__ asrc,
                        const float* __restrict__ adst, const int* __restrict__ row_ptr,
                        const int* __restrict__ esrc, const float* __restrict__ bias,
                        const float* __restrict__ Wn,
                        const float* __restrict__ a_srcn, const float* __restrict__ a_dstn,
                        const float* __restrict__ avs, const float* __restrict__ avd,
                        float* __restrict__ hout, float* __restrict__ ylin,
                        float* __restrict__ asrco, float* __restrict__ adsto, int n){
  __shared__ float wl[NEXT == 1 ? 4096 : 1];
  if (NEXT == 1){
    for (int q = threadIdx.x; q < 1024; q += 256)
      ((float4*)wl)[q] = ((const float4*)Wn)[q];
    __syncthreads();
  }
  int node = (blockIdx.x * blockDim.x + threadIdx.x) >> 6;
  if (node >= n) return;
  int lane = threadIdx.x & 63;
  int h = lane >> 3;
  int j = lane & 7;
  int beg = row_ptr[node], end = row_ptr[node + 1];
  float ad = adst[node * 8 + h];
  float m = -INFINITY;
  for (int p = beg + j; p < end; p += 8)
    m = fmaxf(m, lrelu(asrc[esrc[p] * 8 + h] + ad));
  m = fmaxf(m, __shfl_xor(m, 1));
  m = fmaxf(m, __shfl_xor(m, 2));
  m = fmaxf(m, __shfl_xor(m, 4));
  float acc = 0.f, swp = 0.f;
  int hb = lane & 56;
  for (int b0 = beg; b0 < end; b0 += 8){
    int p = b0 + j;
    float w = 0.f; int s = 0;
    if (p < end){ s = esrc[p]; w = __expf(lrelu(asrc[s * 8 + h] + ad) - m); }
    swp += w;
    int cnt = end - b0; if (cnt > 8) cnt = 8;
    if (cnt == 8){
#pragma unroll
      for (int i = 0; i < 8; ++i){
        int   si = __shfl(s, i);
        float hv = hlin[(size_t)si * 64 + lane];
        float wi = __shfl(w, hb + i);
        acc += hv * wi;
      }
    } else {
      for (int i = 0; i < cnt; ++i){
        int   si = __shfl(s, i);
        float hv = hlin[(size_t)si * 64 + lane];
        float wi = __shfl(w, hb + i);
        acc += hv * wi;
      }
    }
  }
  swp += __shfl_xor(swp, 1);
  swp += __shfl_xor(swp, 2);
  swp += __shfl_xor(swp, 4);
  float o = eluf(acc / swp + bias[lane]);   // this node's h row, lane = channel

  if (NEXT == 1){
    float y = 0.f;
#pragma unroll 8
    for (int c = 0; c < 64; ++c)
      y += __shfl(o, c) * wl[c * 64 + lane];
    ylin[(size_t)node * 64 + lane] = y;
    float s1 = y * a_srcn[lane];
    float s2 = y * a_dstn[lane];
    s1 += __shfl_xor(s1, 1); s1 += __shfl_xor(s1, 2); s1 += __shfl_xor(s1, 4);
    s2 += __shfl_xor(s2, 1); s2 += __shfl_xor(s2, 2); s2 += __shfl_xor(s2, 4);
    if (j == 0)      asrco[node * 8 + h] = s1;
    else if (j == 1) adsto[node * 8 + h] = s2;
  } else {
    hout[(size_t)node * 64 + lane] = o;
    float r0 = o * avs[lane],       r1 = o * avs[64 + lane];
    float r2 = o * avs[128 + lane], r3 = o * avs[192 + lane];
    float d0 = o * avd[lane],       d1 = o * avd[64 + lane];
    float d2 = o * avd[128 + lane], d3 = o * avd[192 + lane];
#pragma unroll
    for (int off = 1; off < 64; off <<= 1){
      r0 += __shfl_xor(r0, off); r1 += __shfl_xor(r1, off);
      r2 += __shfl_xor(r2, off); r3 += __shfl_xor(r3, off);
      d0 += __shfl_xor(d0, off); d1 += __shfl_xor(d1, off);
      d2 += __shfl_xor(d2, off); d3 += __shfl_xor(d3, off);
    }
    if (lane == 0){
      asrco[node * 4 + 0] = r0; asrco[node * 4 + 1] = r1;
      asrco[node * 4 + 2] = r2; asrco[node * 4 + 3] = r3;
      adsto[node * 4 + 0] = d0; adsto[node * 4 + 1] = d1;
      adsto[node * 4 + 2] = d2; adsto[node * 4 + 3] = d3;
    }
  }
}

// Layer-4 gather: z[n, h*64+c] = sum_e w_e h3[s_e, c] / sw_h. (edge-batched)
__global__ void aggz_k(const float* __restrict__ h3, const float* __restrict__ asrc,
                       const float* __restrict__ adst, const int* __restrict__ row_ptr,
                       const int* __restrict__ esrc, float* __restrict__ z, int n){
  int node = (blockIdx.x * blockDim.x + threadIdx.x) >> 6;
  if (node >= n) return;
  int lane = threadIdx.x & 63;
  int h = lane >> 4, j = lane & 15;
  int beg = row_ptr[node], end = row_ptr[node + 1];
  float4 adv = *(const float4*)(adst + (size_t)node * 4);
  float adh = h == 0 ? adv.x : h == 1 ? adv.y : h == 2 ? adv.z : adv.w;
  float m = -INFINITY;
  for (int p = beg + j; p < end; p += 16)
    m = fmaxf(m, lrelu(asrc[esrc[p] * 4 + h] + adh));
  m = fmaxf(m, __shfl_xor(m, 1));
  m = fmaxf(m, __shfl_xor(m, 2));
  m = fmaxf(m, __shfl_xor(m, 4));
  m = fmaxf(m, __shfl_xor(m, 8));
  float acc0 = 0.f, acc1 = 0.f, acc2 = 0.f, acc3 = 0.f, swp = 0.f;
  for (int b0 = beg; b0 < end; b0 += 16){
    int p = b0 + j;
    float w = 0.f; int s = 0;
    if (p < end){ s = esrc[p]; w = __expf(lrelu(asrc[s * 4 + h] + adh) - m); }
    swp += w;
    int cnt = end - b0; if (cnt > 16) cnt = 16;
    if (cnt == 16){
#pragma unroll
      for (int i = 0; i < 16; ++i){
        int   si = __shfl(s, i);
        float hv = h3[(size_t)si * 64 + lane];
        float w0 = __shfl(w, i);
        float w1 = __shfl(w, 16 + i);
        float w2 = __shfl(w, 32 + i);
        float w3 = __shfl(w, 48 + i);
        acc0 += hv * w0; acc1 += hv * w1; acc2 += hv * w2; acc3 += hv * w3;
      }
    } else {
      for (int i = 0; i < cnt; ++i){
        int   si = __shfl(s, i);
        float hv = h3[(size_t)si * 64 + lane];
        float w0 = __shfl(w, i);
        float w1 = __shfl(w, 16 + i);
        float w2 = __shfl(w, 32 + i);
        float w3 = __shfl(w, 48 + i);
        acc0 += hv * w0; acc1 += hv * w1; acc2 += hv * w2; acc3 += hv * w3;
      }
    }
  }
  swp += __shfl_xor(swp, 1);
  swp += __shfl_xor(swp, 2);
  swp += __shfl_xor(swp, 4);
  swp += __shfl_xor(swp, 8);
  float sw0 = __shfl(swp, 0), sw1 = __shfl(swp, 16);
  float sw2 = __shfl(swp, 32), sw3 = __shfl(swp, 48);
  size_t zb = (size_t)node * 256;
  z[zb + lane]        = acc0 / sw0;
  z[zb + 64 + lane]   = acc1 / sw1;
  z[zb + 128 + lane]  = acc2 / sw2;
  z[zb + 192 + lane]  = acc3 / sw3;
}

// ---------------- pooling + head ----------------

__global__ void pool_k(const float* __restrict__ h, const int* __restrict__ fidx,
                       const int* __restrict__ flag_arr, float* __restrict__ fp, int m){
  __shared__ float acc[512];
  for (int t = threadIdx.x; t < 512; t += blockDim.x) acc[t] = 0.f;
  __syncthreads();
  int lane = threadIdx.x & 63;
  int wave = (blockIdx.x * blockDim.x + threadIdx.x) >> 6;
  int nwaves = (gridDim.x * blockDim.x) >> 6;
  for (int i = wave; i < m; i += nwaves){
    int g = flag_arr[i];
    int node = fidx[i];
    atomicAdd(&acc[g * 64 + lane], h[(size_t)node * 64 + lane]);
  }
  __syncthreads();
  for (int t = threadIdx.x; t < 512; t += blockDim.x)
    atomicAdd(&fp[t], acc[t]);
}

__global__ void final_k(const float* __restrict__ fp, const float* __restrict__ h,
                        const int* __restrict__ dec,
                        const float* __restrict__ Wp, const float* __restrict__ Wt,
                        const float* __restrict__ Wo, const float* __restrict__ bo,
                        void* __restrict__ out, const int* __restrict__ dflag){
  int g = threadIdx.x >> 6;
  int j = threadIdx.x & 63;
  const float* fr = fp + g * 64;
  const float* tr = h + (size_t)dec[g] * 64;
  float a = 0.f, b = 0.f;
  for (int k = 0; k < 64; ++k){
    a += fr[k] * Wp[k * 64 + j];
    b += tr[k] * Wt[k * 64 + j];
  }
  float v = eluf(a) * Wo[j] + eluf(b) * Wo[64 + j];
  for (int off = 32; off > 0; off >>= 1) v += __shfl_down(v, off);
  if (j == 0){
    float r = v + bo[0];
    if (*dflag) ((float*)out)[g] = r;
    else        ((bf16*)out)[g] = __float2bfloat16(r);
  }
}

// ---------------- launch (14 dispatches) ----------------

extern "C" void kernel_launch(void* const* d_in, const int* in_sizes, int n_in,
                              void* d_out, int out_size, void* d_ws, size_t ws_size,
                              hipStream_t stream) {
  const int*  ei    = (const int*)d_in[1];
  const int*  fidx  = (const int*)d_in[2];
  const int*  flagg = (const int*)d_in[3];
  const int*  dec   = (const int*)d_in[4];

  const int N = in_sizes[0] / 16;   // 20000
  const int E = in_sizes[1] / 2;    // 320000
  const int M = in_sizes[2];        // 8000
  const int ET = E + N;

  const int fidxs[21] = {0,5,6,7,8,9,10,11,12,13,14,15,16,17,18,19,20,21,22,23,24};
  ConvDesc cd;
  int tot = 0;
  for (int k = 0; k < 21; ++k){
    cd.src[k] = d_in[fidxs[k]];
    cd.off[k] = tot;
    tot += in_sizes[fidxs[k]];
  }
  cd.off[21] = tot;

  char* p = (char*)d_ws;
  auto carve = [&](size_t bytes) -> void* {
    void* r = (void*)p;
    p += (bytes + 255) & ~(size_t)255;
    return r;
  };
  int*   dflag   = (int*)carve(4);
  float* conv    = (float*)carve((size_t)tot * 4);
  float* hlA     = (float*)carve((size_t)N * 64 * 4);
  float* hlB     = (float*)carve((size_t)N * 64 * 4);
  float* h3buf   = (float*)carve((size_t)N * 64 * 4);
  float* zbuf    = (float*)carve((size_t)N * 256 * 4);
  float* h4buf   = (float*)carve((size_t)N * 64 * 4);
  float* asrcA   = (float*)carve((size_t)N * 8 * 4);
  float* adstA   = (float*)carve((size_t)N * 8 * 4);
  float* asrcB   = (float*)carve((size_t)N * 8 * 4);
  float* adstB   = (float*)carve((size_t)N * 8 * 4);
  int*   counts  = (int*)carve((size_t)N * 4);
  int*   row_ptr = (int*)carve((size_t)(N + 1) * 4);
  int*   esrc    = (int*)carve((size_t)ET * 4);
  float* fp      = (float*)carve(8 * 64 * 4);
  float* avs     = (float*)carve(256 * 4);
  float* avd     = (float*)carve(256 * 4);
  float* wz      = (float*)carve(256 * 64 * 4);

  if ((size_t)(p - (char*)d_ws) > ws_size) return;

  const float* cW1 = conv + cd.off[1],  *cas1 = conv + cd.off[2],  *cad1 = conv + cd.off[3],  *cb1 = conv + cd.off[4];
  const float* cW2 = conv + cd.off[5],  *cas2 = conv + cd.off[6],  *cad2 = conv + cd.off[7],  *cb2 = conv + cd.off[8];
  const float* cW3 = conv + cd.off[9],  *cas3 = conv + cd.off[10], *cad3 = conv + cd.off[11], *cb3 = conv + cd.off[12];
  const float* cW4 = conv + cd.off[13], *cas4 = conv + cd.off[14], *cad4 = conv + cd.off[15], *cb4 = conv + cd.off[16];
  const float* cWp = conv + cd.off[17], *cWt = conv + cd.off[18], *cWo = conv + cd.off[19], *cbo = conv + cd.off[20];
  const float* xf  = conv + cd.off[0];

  const int TB = 256;

  // 1: dtype probe (self-zeroing)
  int nprobe = in_sizes[0] < 4096 ? in_sizes[0] : 4096;
  detect_k<<<1, TB, 0, stream>>>((const unsigned short*)d_in[0], nprobe, dflag);
  // 2: convert + zero counts/fp
  convert_all_k<<<(tot + TB - 1) / TB, TB, 0, stream>>>(cd, conv, dflag, tot, counts, fp, N);
  // 3-5: CSR build
  int eb = (ET + TB - 1) / TB;
  count_edges_k<<<eb, TB, 0, stream>>>(ei, counts, E, N);
  scan_k<<<1, 1024, 0, stream>>>(counts, counts, row_ptr, N);
  scatter_k<<<eb, TB, 0, stream>>>(ei, row_ptr, counts, esrc, E, N);
  // 6: layer-4 prep
  prep4_k<<<64, TB, 0, stream>>>(cW4, cas4, cad4, avs, avd, wz);

  int agg_blocks = (N * 64 + TB - 1) / TB;
  int ls_blocks  = (N + 15) / 16;

  // 7: layer-1 linear + alpha1 -> A
  linear_s_k<16, false, true><<<ls_blocks, TB, 0, stream>>>(xf, cW1, nullptr, cas1, cad1, hlA, asrcA, adstA, N);
  // 8: agg1(reads A) + lin2 + alpha2 -> B
  agg8f_k<1><<<agg_blocks, TB, 0, stream>>>(hlA, asrcA, adstA, row_ptr, esrc, cb1,
                                            cW2, cas2, cad2, nullptr, nullptr,
                                            nullptr, hlB, asrcB, adstB, N);
  // 9: agg2(reads B) + lin3 + alpha3 -> A
  agg8f_k<1><<<agg_blocks, TB, 0, stream>>>(hlB, asrcB, adstB, row_ptr, esrc, cb2,
                                            cW3, cas3, cad3, nullptr, nullptr,
                                            nullptr, hlA, asrcA, adstA, N);
  // 10: agg3(reads A, stores h3) + alpha4 -> B
  agg8f_k<2><<<agg_blocks, TB, 0, stream>>>(hlA, asrcA, adstA, row_ptr, esrc, cb3,
                                            nullptr, nullptr, nullptr, avs, avd,
                                            h3buf, nullptr, asrcB, adstB, N);
  // 11: layer-4 gather (reads B)
  aggz_k<<<agg_blocks, TB, 0, stream>>>(h3buf, asrcB, adstB, row_ptr, esrc, zbuf, N);
  // 12: z @ Wz + bias + elu
  linear_s_k<256, true, false><<<ls_blocks, TB, 0, stream>>>(zbuf, wz, cb4, nullptr, nullptr, h4buf, nullptr, nullptr, N);
  // 13-14: pool + head
  pool_k<<<64, TB, 0, stream>>>(h4buf, fidx, flagg, fp, M);
  final_k<<<1, 512, 0, stream>>>(fp, h4buf, dec, cWp, cWt, cWo, cbo, d_out, dflag);
}

// Round 11
// 375.219 us; speedup vs baseline: 1.2886x; 1.0018x over previous
//
#include <hip/hip_runtime.h>
#include <hip/hip_bf16.h>
#include <math.h>

typedef __hip_bfloat16 bf16;

__device__ __forceinline__ float b2f(bf16 v){ return __bfloat162float(v); }
__device__ __forceinline__ float eluf(float x){ return x > 0.f ? x : __expf(x) - 1.f; }
__device__ __forceinline__ float lrelu(float x){ return x > 0.f ? x : 0.2f * x; }

// ---------------- dtype detection (self-contained, no pre-zero) -------------
__global__ void detect_k(const unsigned short* __restrict__ u16, int n, int* __restrict__ flag){
  __shared__ int bad_s;
  if (threadIdx.x == 0) bad_s = 0;
  __syncthreads();
  int bad = 0;
  for (int k = threadIdx.x; k < n; k += 256){
    int ex = (u16[k] >> 7) & 0xFF;
    if (ex >= 0xC6) bad = 1;
  }
  if (bad) atomicOr(&bad_s, 1);
  __syncthreads();
  if (threadIdx.x == 0) *flag = bad_s;
}

// ---------------- unified input conversion to fp32 (+ zero counts/fp) -------
struct ConvDesc {
  const void* src[21];
  int off[22];
};

__global__ void convert_all_k(ConvDesc d, float* __restrict__ out,
                              const int* __restrict__ flag, int total,
                              int* __restrict__ counts, float* __restrict__ fp, int n){
  int i = blockIdx.x * blockDim.x + threadIdx.x;
  if (i < n) counts[i] = 0;
  if (i < 512) fp[i] = 0.f;
  if (i >= total) return;
  int a = 0;
  while (i >= d.off[a + 1]) ++a;
  int j = i - d.off[a];
  float v;
  if (*flag) v = ((const float*)d.src[a])[j];
  else       v = b2f(((const bf16*)d.src[a])[j]);
  out[i] = v;
}

// ---------------- CSR build ----------------

__global__ void count_edges_k(const int* __restrict__ ei, int* __restrict__ counts, int E, int n){
  int e = blockIdx.x * blockDim.x + threadIdx.x;
  if (e >= E + n) return;
  int d = (e < E) ? ei[E + e] : (e - E);
  atomicAdd(&counts[d], 1);
}

__global__ void scan_k(const int* __restrict__ counts_in, int* __restrict__ counts_zero,
                       int* __restrict__ row_ptr, int n){
  __shared__ int psum[1024];
  int t = threadIdx.x;
  int chunk = (n + 1023) >> 10;
  int beg = t * chunk;
  int end = beg + chunk; if (end > n) end = n;
  int s = 0;
  for (int i = beg; i < end; ++i) s += counts_in[i];
  psum[t] = s;
  __syncthreads();
  for (int off = 1; off < 1024; off <<= 1){
    int v = (t >= off) ? psum[t - off] : 0;
    __syncthreads();
    psum[t] += v;
    __syncthreads();
  }
  int run = psum[t] - s;
  for (int i = beg; i < end; ++i){
    row_ptr[i] = run; run += counts_in[i]; counts_zero[i] = 0;
  }
  if (beg < n && end == n) row_ptr[n] = run;
}

__global__ void scatter_k(const int* __restrict__ ei, const int* __restrict__ row_ptr,
                          int* __restrict__ fill, int* __restrict__ esrc, int E, int n){
  int e = blockIdx.x * blockDim.x + threadIdx.x;
  if (e >= E + n) return;
  int s, d;
  if (e < E){ s = ei[e]; d = ei[E + e]; } else { s = e - E; d = s; }
  int pos = row_ptr[d] + atomicAdd(&fill[d], 1);
  esrc[pos] = s;
}

// ---------------- small-tile linear: 16 nodes/block ----------
template<int K, bool ELU, bool ALPHA>
__global__ void linear_s_k(const float* __restrict__ X, const float* __restrict__ W,
                           const float* __restrict__ bias,
                           const float* __restrict__ a_src, const float* __restrict__ a_dst,
                           float* __restrict__ Y, float* __restrict__ asrc,
                           float* __restrict__ adst, int n){
  constexpr int KC = (K > 64) ? 64 : K;
  __shared__ float wl[KC * 64];
  __shared__ float xt[KC][17];
  int base = blockIdx.x * 16;
  int t = threadIdx.x;
  int lane = t & 63, wv = t >> 6;
  int node = wv * 4 + (lane >> 4);
  int jj = lane & 15;
  float ax = 0.f, ay = 0.f, az = 0.f, aw = 0.f;
  for (int kb = 0; kb < K; kb += KC){
    if (kb) __syncthreads();
    for (int q = t; q < KC * 16; q += 256)
      ((float4*)wl)[q] = ((const float4*)(W + (size_t)(kb + (q >> 4)) * 64))[q & 15];
    for (int q = t; q < 16 * (KC / 4); q += 256){
      int nd = q / (KC / 4);
      int k4 = q - nd * (KC / 4);
      float4 v = make_float4(0.f, 0.f, 0.f, 0.f);
      if (base + nd < n) v = *(const float4*)(X + (size_t)(base + nd) * K + kb + k4 * 4);
      xt[k4 * 4 + 0][nd] = v.x;
      xt[k4 * 4 + 1][nd] = v.y;
      xt[k4 * 4 + 2][nd] = v.z;
      xt[k4 * 4 + 3][nd] = v.w;
    }
    __syncthreads();
#pragma unroll 8
    for (int k = 0; k < KC; ++k){
      float xv = xt[k][node];
      float4 w = ((const float4*)wl)[k * 16 + jj];
      ax += xv * w.x; ay += xv * w.y; az += xv * w.z; aw += xv * w.w;
    }
  }
  int gn = base + node;
  if (ELU){
    if (gn < n){
      float4 b = ((const float4*)bias)[jj];
      ((float4*)(Y + (size_t)gn * 64))[jj] =
        make_float4(eluf(ax + b.x), eluf(ay + b.y), eluf(az + b.z), eluf(aw + b.w));
    }
  } else {
    if (gn < n)
      ((float4*)(Y + (size_t)gn * 64))[jj] = make_float4(ax, ay, az, aw);
  }
  if (ALPHA){
    float4 as = *(const float4*)(a_src + 4 * jj);
    float4 ad = *(const float4*)(a_dst + 4 * jj);
    float s1 = ax * as.x + ay * as.y + az * as.z + aw * as.w;
    float s2 = ax * ad.x + ay * ad.y + az * ad.z + aw * ad.w;
    s1 += __shfl_xor(s1, 1);
    s2 += __shfl_xor(s2, 1);
    if (gn < n){
      int h = jj >> 1;
      if ((jj & 1) == 0) asrc[gn * 8 + h] = s1;
      else               adst[gn * 8 + h] = s2;
    }
  }
}

// ---------------- layer-4 prep ----------------
__global__ void prep4_k(const float* __restrict__ W4, const float* __restrict__ as4,
                        const float* __restrict__ ad4, float* __restrict__ avs,
                        float* __restrict__ avd, float* __restrict__ Wz){
  int g = blockIdx.x * 256 + threadIdx.x;
  int r = g >> 6, c = g & 63;
  int h = r >> 6, k = r & 63;
  Wz[(size_t)r * 64 + c] = 0.25f * W4[(size_t)k * 256 + h * 64 + c];
  if (blockIdx.x == 0){
    int t = threadIdx.x;
    int th = t >> 6, tk = t & 63;
    const float* wr = W4 + (size_t)tk * 256 + th * 64;
    const float* sr = as4 + th * 64;
    const float* dr = ad4 + th * 64;
    float s1 = 0.f, s2 = 0.f;
    for (int cc = 0; cc < 64; ++cc){ float w = wr[cc]; s1 += w * sr[cc]; s2 += w * dr[cc]; }
    avs[t] = s1;
    avd[t] = s2;
  }
}

// ---------------- fused agg8, ONLINE softmax + batch prefetch ---------------
// Round-10 postmortem: the separate max pre-pass (serial scattered load chain)
// was ~40% of the gather kernel. Online rescale (exact, flash-style) removes
// it; next batch's esrc/alpha prefetched in the shadow of the 8 row-gathers.
// Alpha ping-pong preserved (round-9 race fix).
template<int NEXT>
__global__ void agg8f_k(const float* __restrict__ hlin, const float* __restrict__ asrc,
                        const float* __restrict__ adst, const int* __restrict__ row_ptr,
                        const int* __restrict__ esrc, const float* __restrict__ bias,
                        const float* __restrict__ Wn,
                        const float* __restrict__ a_srcn, const float* __restrict__ a_dstn,
                        const float* __restrict__ avs, const float* __restrict__ avd,
                        float* __restrict__ hout, float* __restrict__ ylin,
                        float* __restrict__ asrco, float* __restrict__ adsto, int n){
  __shared__ float wl[NEXT == 1 ? 4096 : 1];
  if (NEXT == 1){
    for (int q = threadIdx.x; q < 1024; q += 256)
      ((float4*)wl)[q] = ((const float4*)Wn)[q];
    __syncthreads();
  }
  int node = (blockIdx.x * blockDim.x + threadIdx.x) >> 6;
  if (node >= n) return;
  int lane = threadIdx.x & 63;
  int h = lane >> 3;
  int j = lane & 7;
  int beg = row_ptr[node], end = row_ptr[node + 1];
  float ad = adst[node * 8 + h];
  int hb = lane & 56;

  float m = -INFINITY, acc = 0.f, swp = 0.f;
  // prefetch first batch
  int p0 = beg + j;
  int   s_nx = 0;
  float l_nx = -INFINITY;
  if (p0 < end){ s_nx = esrc[p0]; l_nx = lrelu(asrc[s_nx * 8 + h] + ad); }
  for (int b0 = beg; b0 < end; b0 += 8){
    int   s = s_nx;
    float l = l_nx;
    int p2 = b0 + 8 + j;
    s_nx = 0; l_nx = -INFINITY;
    if (p2 < end){ s_nx = esrc[p2]; l_nx = lrelu(asrc[s_nx * 8 + h] + ad); }
    // online max update (per head: lanes hb..hb+7)
    float bm = l;
    bm = fmaxf(bm, __shfl_xor(bm, 1));
    bm = fmaxf(bm, __shfl_xor(bm, 2));
    bm = fmaxf(bm, __shfl_xor(bm, 4));
    float mn = fmaxf(m, bm);
    float scale = __expf(m - mn);   // first batch: exp(-inf)=0, acc/swp already 0
    acc *= scale; swp *= scale; m = mn;
    float w = (b0 + j < end) ? __expf(l - m) : 0.f;
    swp += w;
    int cnt = end - b0; if (cnt > 8) cnt = 8;
    if (cnt == 8){
#pragma unroll
      for (int i = 0; i < 8; ++i){
        int   si = __shfl(s, i);
        float hv = hlin[(size_t)si * 64 + lane];
        float wi = __shfl(w, hb + i);
        acc += hv * wi;
      }
    } else {
      for (int i = 0; i < cnt; ++i){
        int   si = __shfl(s, i);
        float hv = hlin[(size_t)si * 64 + lane];
        float wi = __shfl(w, hb + i);
        acc += hv * wi;
      }
    }
  }
  swp += __shfl_xor(swp, 1);
  swp += __shfl_xor(swp, 2);
  swp += __shfl_xor(swp, 4);
  float o = eluf(acc / swp + bias[lane]);

  if (NEXT == 1){
    float y = 0.f;
#pragma unroll 8
    for (int c = 0; c < 64; ++c)
      y += __shfl(o, c) * wl[c * 64 + lane];
    ylin[(size_t)node * 64 + lane] = y;
    float s1 = y * a_srcn[lane];
    float s2 = y * a_dstn[lane];
    s1 += __shfl_xor(s1, 1); s1 += __shfl_xor(s1, 2); s1 += __shfl_xor(s1, 4);
    s2 += __shfl_xor(s2, 1); s2 += __shfl_xor(s2, 2); s2 += __shfl_xor(s2, 4);
    if (j == 0)      asrco[node * 8 + h] = s1;
    else if (j == 1) adsto[node * 8 + h] = s2;
  } else {
    hout[(size_t)node * 64 + lane] = o;
    float r0 = o * avs[lane],       r1 = o * avs[64 + lane];
    float r2 = o * avs[128 + lane], r3 = o * avs[192 + lane];
    float d0 = o * avd[lane],       d1 = o * avd[64 + lane];
    float d2 = o * avd[128 + lane], d3 = o * avd[192 + lane];
#pragma unroll
    for (int off = 1; off < 64; off <<= 1){
      r0 += __shfl_xor(r0, off); r1 += __shfl_xor(r1, off);
      r2 += __shfl_xor(r2, off); r3 += __shfl_xor(r3, off);
      d0 += __shfl_xor(d0, off); d1 += __shfl_xor(d1, off);
      d2 += __shfl_xor(d2, off); d3 += __shfl_xor(d3, off);
    }
    if (lane == 0){
      asrco[node * 4 + 0] = r0; asrco[node * 4 + 1] = r1;
      asrco[node * 4 + 2] = r2; asrco[node * 4 + 3] = r3;
      adsto[node * 4 + 0] = d0; adsto[node * 4 + 1] = d1;
      adsto[node * 4 + 2] = d2; adsto[node * 4 + 3] = d3;
    }
  }
}

// Layer-4 gather, ONLINE softmax + prefetch. 16-edge x 4-head batches.
__global__ void aggz_k(const float* __restrict__ h3, const float* __restrict__ asrc,
                       const float* __restrict__ adst, const int* __restrict__ row_ptr,
                       const int* __restrict__ esrc, float* __restrict__ z, int n){
  int node = (blockIdx.x * blockDim.x + threadIdx.x) >> 6;
  if (node >= n) return;
  int lane = threadIdx.x & 63;
  int h = lane >> 4, j = lane & 15;
  int beg = row_ptr[node], end = row_ptr[node + 1];
  float4 adv = *(const float4*)(adst + (size_t)node * 4);
  float adh = h == 0 ? adv.x : h == 1 ? adv.y : h == 2 ? adv.z : adv.w;

  float m = -INFINITY;
  float acc0 = 0.f, acc1 = 0.f, acc2 = 0.f, acc3 = 0.f, swp = 0.f;
  int p0 = beg + j;
  int   s_nx = 0;
  float l_nx = -INFINITY;
  if (p0 < end){ s_nx = esrc[p0]; l_nx = lrelu(asrc[s_nx * 4 + h] + adh); }
  for (int b0 = beg; b0 < end; b0 += 16){
    int   s = s_nx;
    float l = l_nx;
    int p2 = b0 + 16 + j;
    s_nx = 0; l_nx = -INFINITY;
    if (p2 < end){ s_nx = esrc[p2]; l_nx = lrelu(asrc[s_nx * 4 + h] + adh); }
    float bm = l;
    bm = fmaxf(bm, __shfl_xor(bm, 1));
    bm = fmaxf(bm, __shfl_xor(bm, 2));
    bm = fmaxf(bm, __shfl_xor(bm, 4));
    bm = fmaxf(bm, __shfl_xor(bm, 8));
    float mn = fmaxf(m, bm);
    float scale = __expf(m - mn);
    acc0 *= scale; acc1 *= scale; acc2 *= scale; acc3 *= scale;
    swp *= scale; m = mn;
    float w = (b0 + j < end) ? __expf(l - m) : 0.f;
    swp += w;
    int cnt = end - b0; if (cnt > 16) cnt = 16;
    if (cnt == 16){
#pragma unroll
      for (int i = 0; i < 16; ++i){
        int   si = __shfl(s, i);
        float hv = h3[(size_t)si * 64 + lane];
        float w0 = __shfl(w, i);
        float w1 = __shfl(w, 16 + i);
        float w2 = __shfl(w, 32 + i);
        float w3 = __shfl(w, 48 + i);
        acc0 += hv * w0; acc1 += hv * w1; acc2 += hv * w2; acc3 += hv * w3;
      }
    } else {
      for (int i = 0; i < cnt; ++i){
        int   si = __shfl(s, i);
        float hv = h3[(size_t)si * 64 + lane];
        float w0 = __shfl(w, i);
        float w1 = __shfl(w, 16 + i);
        float w2 = __shfl(w, 32 + i);
        float w3 = __shfl(w, 48 + i);
        acc0 += hv * w0; acc1 += hv * w1; acc2 += hv * w2; acc3 += hv * w3;
      }
    }
  }
  swp += __shfl_xor(swp, 1);
  swp += __shfl_xor(swp, 2);
  swp += __shfl_xor(swp, 4);
  swp += __shfl_xor(swp, 8);
  float sw0 = __shfl(swp, 0), sw1 = __shfl(swp, 16);
  float sw2 = __shfl(swp, 32), sw3 = __shfl(swp, 48);
  size_t zb = (size_t)node * 256;
  z[zb + lane]        = acc0 / sw0;
  z[zb + 64 + lane]   = acc1 / sw1;
  z[zb + 128 + lane]  = acc2 / sw2;
  z[zb + 192 + lane]  = acc3 / sw3;
}

// ---------------- pooling + head ----------------

__global__ void pool_k(const float* __restrict__ h, const int* __restrict__ fidx,
                       const int* __restrict__ flag_arr, float* __restrict__ fp, int m){
  __shared__ float acc[512];
  for (int t = threadIdx.x; t < 512; t += blockDim.x) acc[t] = 0.f;
  __syncthreads();
  int lane = threadIdx.x & 63;
  int wave = (blockIdx.x * blockDim.x + threadIdx.x) >> 6;
  int nwaves = (gridDim.x * blockDim.x) >> 6;
  for (int i = wave; i < m; i += nwaves){
    int g = flag_arr[i];
    int node = fidx[i];
    atomicAdd(&acc[g * 64 + lane], h[(size_t)node * 64 + lane]);
  }
  __syncthreads();
  for (int t = threadIdx.x; t < 512; t += blockDim.x)
    atomicAdd(&fp[t], acc[t]);
}

__global__ void final_k(const float* __restrict__ fp, const float* __restrict__ h,
                        const int* __restrict__ dec,
                        const float* __restrict__ Wp, const float* __restrict__ Wt,
                        const float* __restrict__ Wo, const float* __restrict__ bo,
                        void* __restrict__ out, const int* __restrict__ dflag){
  int g = threadIdx.x >> 6;
  int j = threadIdx.x & 63;
  const float* fr = fp + g * 64;
  const float* tr = h + (size_t)dec[g] * 64;
  float a = 0.f, b = 0.f;
  for (int k = 0; k < 64; ++k){
    a += fr[k] * Wp[k * 64 + j];
    b += tr[k] * Wt[k * 64 + j];
  }
  float v = eluf(a) * Wo[j] + eluf(b) * Wo[64 + j];
  for (int off = 32; off > 0; off >>= 1) v += __shfl_down(v, off);
  if (j == 0){
    float r = v + bo[0];
    if (*dflag) ((float*)out)[g] = r;
    else        ((bf16*)out)[g] = __float2bfloat16(r);
  }
}

// ---------------- launch (14 dispatches) ----------------

extern "C" void kernel_launch(void* const* d_in, const int* in_sizes, int n_in,
                              void* d_out, int out_size, void* d_ws, size_t ws_size,
                              hipStream_t stream) {
  const int*  ei    = (const int*)d_in[1];
  const int*  fidx  = (const int*)d_in[2];
  const int*  flagg = (const int*)d_in[3];
  const int*  dec   = (const int*)d_in[4];

  const int N = in_sizes[0] / 16;   // 20000
  const int E = in_sizes[1] / 2;    // 320000
  const int M = in_sizes[2];        // 8000
  const int ET = E + N;

  const int fidxs[21] = {0,5,6,7,8,9,10,11,12,13,14,15,16,17,18,19,20,21,22,23,24};
  ConvDesc cd;
  int tot = 0;
  for (int k = 0; k < 21; ++k){
    cd.src[k] = d_in[fidxs[k]];
    cd.off[k] = tot;
    tot += in_sizes[fidxs[k]];
  }
  cd.off[21] = tot;

  char* p = (char*)d_ws;
  auto carve = [&](size_t bytes) -> void* {
    void* r = (void*)p;
    p += (bytes + 255) & ~(size_t)255;
    return r;
  };
  int*   dflag   = (int*)carve(4);
  float* conv    = (float*)carve((size_t)tot * 4);
  float* hlA     = (float*)carve((size_t)N * 64 * 4);
  float* hlB     = (float*)carve((size_t)N * 64 * 4);
  float* h3buf   = (float*)carve((size_t)N * 64 * 4);
  float* zbuf    = (float*)carve((size_t)N * 256 * 4);
  float* h4buf   = (float*)carve((size_t)N * 64 * 4);
  float* asrcA   = (float*)carve((size_t)N * 8 * 4);
  float* adstA   = (float*)carve((size_t)N * 8 * 4);
  float* asrcB   = (float*)carve((size_t)N * 8 * 4);
  float* adstB   = (float*)carve((size_t)N * 8 * 4);
  int*   counts  = (int*)carve((size_t)N * 4);
  int*   row_ptr = (int*)carve((size_t)(N + 1) * 4);
  int*   esrc    = (int*)carve((size_t)ET * 4);
  float* fp      = (float*)carve(8 * 64 * 4);
  float* avs     = (float*)carve(256 * 4);
  float* avd     = (float*)carve(256 * 4);
  float* wz      = (float*)carve(256 * 64 * 4);

  if ((size_t)(p - (char*)d_ws) > ws_size) return;

  const float* cW1 = conv + cd.off[1],  *cas1 = conv + cd.off[2],  *cad1 = conv + cd.off[3],  *cb1 = conv + cd.off[4];
  const float* cW2 = conv + cd.off[5],  *cas2 = conv + cd.off[6],  *cad2 = conv + cd.off[7],  *cb2 = conv + cd.off[8];
  const float* cW3 = conv + cd.off[9],  *cas3 = conv + cd.off[10], *cad3 = conv + cd.off[11], *cb3 = conv + cd.off[12];
  const float* cW4 = conv + cd.off[13], *cas4 = conv + cd.off[14], *cad4 = conv + cd.off[15], *cb4 = conv + cd.off[16];
  const float* cWp = conv + cd.off[17], *cWt = conv + cd.off[18], *cWo = conv + cd.off[19], *cbo = conv + cd.off[20];
  const float* xf  = conv + cd.off[0];

  const int TB = 256;

  int nprobe = in_sizes[0] < 4096 ? in_sizes[0] : 4096;
  detect_k<<<1, TB, 0, stream>>>((const unsigned short*)d_in[0], nprobe, dflag);
  convert_all_k<<<(tot + TB - 1) / TB, TB, 0, stream>>>(cd, conv, dflag, tot, counts, fp, N);
  int eb = (ET + TB - 1) / TB;
  count_edges_k<<<eb, TB, 0, stream>>>(ei, counts, E, N);
  scan_k<<<1, 1024, 0, stream>>>(counts, counts, row_ptr, N);
  scatter_k<<<eb, TB, 0, stream>>>(ei, row_ptr, counts, esrc, E, N);
  prep4_k<<<64, TB, 0, stream>>>(cW4, cas4, cad4, avs, avd, wz);

  int agg_blocks = (N * 64 + TB - 1) / TB;
  int ls_blocks  = (N + 15) / 16;

  // layer-1 linear + alpha1 -> A
  linear_s_k<16, false, true><<<ls_blocks, TB, 0, stream>>>(xf, cW1, nullptr, cas1, cad1, hlA, asrcA, adstA, N);
  // agg1(A) + lin2 + alpha2 -> B
  agg8f_k<1><<<agg_blocks, TB, 0, stream>>>(hlA, asrcA, adstA, row_ptr, esrc, cb1,
                                            cW2, cas2, cad2, nullptr, nullptr,
                                            nullptr, hlB, asrcB, adstB, N);
  // agg2(B) + lin3 + alpha3 -> A
  agg8f_k<1><<<agg_blocks, TB, 0, stream>>>(hlB, asrcB, adstB, row_ptr, esrc, cb2,
                                            cW3, cas3, cad3, nullptr, nullptr,
                                            nullptr, hlA, asrcA, adstA, N);
  // agg3(A, stores h3) + alpha4 -> B
  agg8f_k<2><<<agg_blocks, TB, 0, stream>>>(hlA, asrcA, adstA, row_ptr, esrc, cb3,
                                            nullptr, nullptr, nullptr, avs, avd,
                                            h3buf, nullptr, asrcB, adstB, N);
  // layer-4 gather (B)
  aggz_k<<<agg_blocks, TB, 0, stream>>>(h3buf, asrcB, adstB, row_ptr, esrc, zbuf, N);
  // z @ Wz + bias + elu
  linear_s_k<256, true, false><<<ls_blocks, TB, 0, stream>>>(zbuf, wz, cb4, nullptr, nullptr, h4buf, nullptr, nullptr, N);
  // pool + head
  pool_k<<<64, TB, 0, stream>>>(h4buf, fidx, flagg, fp, M);
  final_k<<<1, 512, 0, stream>>>(fp, h4buf, dec, cWp, cWt, cWo, cbo, d_out, dflag);
}

// Round 12
// 366.260 us; speedup vs baseline: 1.3201x; 1.0245x over previous
//
#include <hip/hip_runtime.h>
#include <hip/hip_bf16.h>
#include <math.h>

typedef __hip_bfloat16 bf16;
typedef unsigned short u16;

__device__ __forceinline__ float b2f(bf16 v){ return __bfloat162float(v); }
__device__ __forceinline__ u16 f2bu(float f){
  bf16 h = __float2bfloat16(f);
  return *reinterpret_cast<u16*>(&h);
}
__device__ __forceinline__ float bu2f(u16 u){
  bf16 h = *reinterpret_cast<bf16*>(&u);
  return __bfloat162float(h);
}
__device__ __forceinline__ float eluf(float x){ return x > 0.f ? x : __expf(x) - 1.f; }
__device__ __forceinline__ float lrelu(float x){ return x > 0.f ? x : 0.2f * x; }

// ---------------- dtype detection ----------------
__global__ void detect_k(const u16* __restrict__ u16p, int n, int* __restrict__ flag){
  __shared__ int bad_s;
  if (threadIdx.x == 0) bad_s = 0;
  __syncthreads();
  int bad = 0;
  for (int k = threadIdx.x; k < n; k += 256){
    int ex = (u16p[k] >> 7) & 0xFF;
    if (ex >= 0xC6) bad = 1;
  }
  if (bad) atomicOr(&bad_s, 1);
  __syncthreads();
  if (threadIdx.x == 0) *flag = bad_s;
}

// ---------------- unified input conversion to fp32 (+ zero counts/fp) -------
struct ConvDesc {
  const void* src[21];
  int off[22];
};

__global__ void convert_all_k(ConvDesc d, float* __restrict__ out,
                              const int* __restrict__ flag, int total,
                              int* __restrict__ counts, float* __restrict__ fp, int n){
  int i = blockIdx.x * blockDim.x + threadIdx.x;
  if (i < n) counts[i] = 0;
  if (i < 512) fp[i] = 0.f;
  if (i >= total) return;
  int a = 0;
  while (i >= d.off[a + 1]) ++a;
  int j = i - d.off[a];
  float v;
  if (*flag) v = ((const float*)d.src[a])[j];
  else       v = b2f(((const bf16*)d.src[a])[j]);
  out[i] = v;
}

// ---------------- CSR build ----------------

__global__ void count_edges_k(const int* __restrict__ ei, int* __restrict__ counts, int E, int n){
  int e = blockIdx.x * blockDim.x + threadIdx.x;
  if (e >= E + n) return;
  int d = (e < E) ? ei[E + e] : (e - E);
  atomicAdd(&counts[d], 1);
}

__global__ void scan_k(const int* __restrict__ counts_in, int* __restrict__ counts_zero,
                       int* __restrict__ row_ptr, int n){
  __shared__ int psum[1024];
  int t = threadIdx.x;
  int chunk = (n + 1023) >> 10;
  int beg = t * chunk;
  int end = beg + chunk; if (end > n) end = n;
  int s = 0;
  for (int i = beg; i < end; ++i) s += counts_in[i];
  psum[t] = s;
  __syncthreads();
  for (int off = 1; off < 1024; off <<= 1){
    int v = (t >= off) ? psum[t - off] : 0;
    __syncthreads();
    psum[t] += v;
    __syncthreads();
  }
  int run = psum[t] - s;
  for (int i = beg; i < end; ++i){
    row_ptr[i] = run; run += counts_in[i]; counts_zero[i] = 0;
  }
  if (beg < n && end == n) row_ptr[n] = run;
}

__global__ void scatter_k(const int* __restrict__ ei, const int* __restrict__ row_ptr,
                          int* __restrict__ fill, int* __restrict__ esrc, int E, int n){
  int e = blockIdx.x * blockDim.x + threadIdx.x;
  if (e >= E + n) return;
  int s, d;
  if (e < E){ s = ei[e]; d = ei[E + e]; } else { s = e - E; d = s; }
  int pos = row_ptr[d] + atomicAdd(&fill[d], 1);
  esrc[pos] = s;
}

// ---------------- small-tile linear: 16 nodes/block ----------
// OB16: output stored as bf16 (h arrays live in bf16 so all 4 gather passes
// fit the 2.56MB array in each XCD's 4MiB L2 — round-12 theory).
template<int K, bool ELU, bool ALPHA, bool OB16>
__global__ void linear_s_k(const float* __restrict__ X, const float* __restrict__ W,
                           const float* __restrict__ bias,
                           const float* __restrict__ a_src, const float* __restrict__ a_dst,
                           float* __restrict__ Y, u16* __restrict__ Yb,
                           float* __restrict__ asrc, float* __restrict__ adst, int n){
  constexpr int KC = (K > 64) ? 64 : K;
  __shared__ float wl[KC * 64];
  __shared__ float xt[KC][17];
  int base = blockIdx.x * 16;
  int t = threadIdx.x;
  int lane = t & 63, wv = t >> 6;
  int node = wv * 4 + (lane >> 4);
  int jj = lane & 15;
  float ax = 0.f, ay = 0.f, az = 0.f, aw = 0.f;
  for (int kb = 0; kb < K; kb += KC){
    if (kb) __syncthreads();
    for (int q = t; q < KC * 16; q += 256)
      ((float4*)wl)[q] = ((const float4*)(W + (size_t)(kb + (q >> 4)) * 64))[q & 15];
    for (int q = t; q < 16 * (KC / 4); q += 256){
      int nd = q / (KC / 4);
      int k4 = q - nd * (KC / 4);
      float4 v = make_float4(0.f, 0.f, 0.f, 0.f);
      if (base + nd < n) v = *(const float4*)(X + (size_t)(base + nd) * K + kb + k4 * 4);
      xt[k4 * 4 + 0][nd] = v.x;
      xt[k4 * 4 + 1][nd] = v.y;
      xt[k4 * 4 + 2][nd] = v.z;
      xt[k4 * 4 + 3][nd] = v.w;
    }
    __syncthreads();
#pragma unroll 8
    for (int k = 0; k < KC; ++k){
      float xv = xt[k][node];
      float4 w = ((const float4*)wl)[k * 16 + jj];
      ax += xv * w.x; ay += xv * w.y; az += xv * w.z; aw += xv * w.w;
    }
  }
  int gn = base + node;
  if (gn < n){
    float vx = ax, vy = ay, vz = az, vw = aw;
    if (ELU){
      float4 b = ((const float4*)bias)[jj];
      vx = eluf(ax + b.x); vy = eluf(ay + b.y); vz = eluf(az + b.z); vw = eluf(aw + b.w);
    }
    if (OB16){
      ushort4 o4;
      o4.x = f2bu(vx); o4.y = f2bu(vy); o4.z = f2bu(vz); o4.w = f2bu(vw);
      ((ushort4*)(Yb + (size_t)gn * 64))[jj] = o4;
    } else {
      ((float4*)(Y + (size_t)gn * 64))[jj] = make_float4(vx, vy, vz, vw);
    }
  }
  if (ALPHA){
    float4 as = *(const float4*)(a_src + 4 * jj);
    float4 ad = *(const float4*)(a_dst + 4 * jj);
    float s1 = ax * as.x + ay * as.y + az * as.z + aw * as.w;
    float s2 = ax * ad.x + ay * ad.y + az * ad.z + aw * ad.w;
    s1 += __shfl_xor(s1, 1);
    s2 += __shfl_xor(s2, 1);
    if (gn < n){
      int h = jj >> 1;
      if ((jj & 1) == 0) asrc[gn * 8 + h] = s1;
      else               adst[gn * 8 + h] = s2;
    }
  }
}

// ---------------- layer-4 prep ----------------
__global__ void prep4_k(const float* __restrict__ W4, const float* __restrict__ as4,
                        const float* __restrict__ ad4, float* __restrict__ avs,
                        float* __restrict__ avd, float* __restrict__ Wz){
  int g = blockIdx.x * 256 + threadIdx.x;
  int r = g >> 6, c = g & 63;
  int h = r >> 6, k = r & 63;
  Wz[(size_t)r * 64 + c] = 0.25f * W4[(size_t)k * 256 + h * 64 + c];
  if (blockIdx.x == 0){
    int t = threadIdx.x;
    int th = t >> 6, tk = t & 63;
    const float* wr = W4 + (size_t)tk * 256 + th * 64;
    const float* sr = as4 + th * 64;
    const float* dr = ad4 + th * 64;
    float s1 = 0.f, s2 = 0.f;
    for (int cc = 0; cc < 64; ++cc){ float w = wr[cc]; s1 += w * sr[cc]; s2 += w * dr[cc]; }
    avs[t] = s1;
    avd[t] = s2;
  }
}

// ---------------- fused agg8 (bf16 h rows, online softmax) ------------------
// Alpha ping-pong preserved (round-9 race fix). h gathers are 2B/lane bf16.
template<int NEXT>
__global__ void agg8f_k(const u16* __restrict__ hlin, const float* __restrict__ asrc,
                        const float* __restrict__ adst, const int* __restrict__ row_ptr,
                        const int* __restrict__ esrc, const float* __restrict__ bias,
                        const float* __restrict__ Wn,
                        const float* __restrict__ a_srcn, const float* __restrict__ a_dstn,
                        const float* __restrict__ avs, const float* __restrict__ avd,
                        u16* __restrict__ hout, u16* __restrict__ ylin,
                        float* __restrict__ asrco, float* __restrict__ adsto, int n){
  __shared__ float wl[NEXT == 1 ? 4096 : 1];
  if (NEXT == 1){
    for (int q = threadIdx.x; q < 1024; q += 256)
      ((float4*)wl)[q] = ((const float4*)Wn)[q];
    __syncthreads();
  }
  int node = (blockIdx.x * blockDim.x + threadIdx.x) >> 6;
  if (node >= n) return;
  int lane = threadIdx.x & 63;
  int h = lane >> 3;
  int j = lane & 7;
  int beg = row_ptr[node], end = row_ptr[node + 1];
  float ad = adst[node * 8 + h];
  int hb = lane & 56;

  float m = -INFINITY, acc = 0.f, swp = 0.f;
  int p0 = beg + j;
  int   s_nx = 0;
  float l_nx = -INFINITY;
  if (p0 < end){ s_nx = esrc[p0]; l_nx = lrelu(asrc[s_nx * 8 + h] + ad); }
  for (int b0 = beg; b0 < end; b0 += 8){
    int   s = s_nx;
    float l = l_nx;
    int p2 = b0 + 8 + j;
    s_nx = 0; l_nx = -INFINITY;
    if (p2 < end){ s_nx = esrc[p2]; l_nx = lrelu(asrc[s_nx * 8 + h] + ad); }
    float bm = l;
    bm = fmaxf(bm, __shfl_xor(bm, 1));
    bm = fmaxf(bm, __shfl_xor(bm, 2));
    bm = fmaxf(bm, __shfl_xor(bm, 4));
    float mn = fmaxf(m, bm);
    float scale = __expf(m - mn);
    acc *= scale; swp *= scale; m = mn;
    float w = (b0 + j < end) ? __expf(l - m) : 0.f;
    swp += w;
    int cnt = end - b0; if (cnt > 8) cnt = 8;
    if (cnt == 8){
#pragma unroll
      for (int i = 0; i < 8; ++i){
        int   si = __shfl(s, i);
        float hv = bu2f(hlin[(size_t)si * 64 + lane]);
        float wi = __shfl(w, hb + i);
        acc += hv * wi;
      }
    } else {
      for (int i = 0; i < cnt; ++i){
        int   si = __shfl(s, i);
        float hv = bu2f(hlin[(size_t)si * 64 + lane]);
        float wi = __shfl(w, hb + i);
        acc += hv * wi;
      }
    }
  }
  swp += __shfl_xor(swp, 1);
  swp += __shfl_xor(swp, 2);
  swp += __shfl_xor(swp, 4);
  float o = eluf(acc / swp + bias[lane]);

  if (NEXT == 1){
    float y = 0.f;
#pragma unroll 8
    for (int c = 0; c < 64; ++c)
      y += __shfl(o, c) * wl[c * 64 + lane];
    ylin[(size_t)node * 64 + lane] = f2bu(y);
    float s1 = y * a_srcn[lane];
    float s2 = y * a_dstn[lane];
    s1 += __shfl_xor(s1, 1); s1 += __shfl_xor(s1, 2); s1 += __shfl_xor(s1, 4);
    s2 += __shfl_xor(s2, 1); s2 += __shfl_xor(s2, 2); s2 += __shfl_xor(s2, 4);
    if (j == 0)      asrco[node * 8 + h] = s1;
    else if (j == 1) adsto[node * 8 + h] = s2;
  } else {
    hout[(size_t)node * 64 + lane] = f2bu(o);
    float r0 = o * avs[lane],       r1 = o * avs[64 + lane];
    float r2 = o * avs[128 + lane], r3 = o * avs[192 + lane];
    float d0 = o * avd[lane],       d1 = o * avd[64 + lane];
    float d2 = o * avd[128 + lane], d3 = o * avd[192 + lane];
#pragma unroll
    for (int off = 1; off < 64; off <<= 1){
      r0 += __shfl_xor(r0, off); r1 += __shfl_xor(r1, off);
      r2 += __shfl_xor(r2, off); r3 += __shfl_xor(r3, off);
      d0 += __shfl_xor(d0, off); d1 += __shfl_xor(d1, off);
      d2 += __shfl_xor(d2, off); d3 += __shfl_xor(d3, off);
    }
    if (lane == 0){
      asrco[node * 4 + 0] = r0; asrco[node * 4 + 1] = r1;
      asrco[node * 4 + 2] = r2; asrco[node * 4 + 3] = r3;
      adsto[node * 4 + 0] = d0; adsto[node * 4 + 1] = d1;
      adsto[node * 4 + 2] = d2; adsto[node * 4 + 3] = d3;
    }
  }
}

// Layer-4 gather (bf16 h3 rows). z stays fp32.
__global__ void aggz_k(const u16* __restrict__ h3, const float* __restrict__ asrc,
                       const float* __restrict__ adst, const int* __restrict__ row_ptr,
                       const int* __restrict__ esrc, float* __restrict__ z, int n){
  int node = (blockIdx.x * blockDim.x + threadIdx.x) >> 6;
  if (node >= n) return;
  int lane = threadIdx.x & 63;
  int h = lane >> 4, j = lane & 15;
  int beg = row_ptr[node], end = row_ptr[node + 1];
  float4 adv = *(const float4*)(adst + (size_t)node * 4);
  float adh = h == 0 ? adv.x : h == 1 ? adv.y : h == 2 ? adv.z : adv.w;

  float m = -INFINITY;
  float acc0 = 0.f, acc1 = 0.f, acc2 = 0.f, acc3 = 0.f, swp = 0.f;
  int p0 = beg + j;
  int   s_nx = 0;
  float l_nx = -INFINITY;
  if (p0 < end){ s_nx = esrc[p0]; l_nx = lrelu(asrc[s_nx * 4 + h] + adh); }
  for (int b0 = beg; b0 < end; b0 += 16){
    int   s = s_nx;
    float l = l_nx;
    int p2 = b0 + 16 + j;
    s_nx = 0; l_nx = -INFINITY;
    if (p2 < end){ s_nx = esrc[p2]; l_nx = lrelu(asrc[s_nx * 4 + h] + adh); }
    float bm = l;
    bm = fmaxf(bm, __shfl_xor(bm, 1));
    bm = fmaxf(bm, __shfl_xor(bm, 2));
    bm = fmaxf(bm, __shfl_xor(bm, 4));
    bm = fmaxf(bm, __shfl_xor(bm, 8));
    float mn = fmaxf(m, bm);
    float scale = __expf(m - mn);
    acc0 *= scale; acc1 *= scale; acc2 *= scale; acc3 *= scale;
    swp *= scale; m = mn;
    float w = (b0 + j < end) ? __expf(l - m) : 0.f;
    swp += w;
    int cnt = end - b0; if (cnt > 16) cnt = 16;
    if (cnt == 16){
#pragma unroll
      for (int i = 0; i < 16; ++i){
        int   si = __shfl(s, i);
        float hv = bu2f(h3[(size_t)si * 64 + lane]);
        float w0 = __shfl(w, i);
        float w1 = __shfl(w, 16 + i);
        float w2 = __shfl(w, 32 + i);
        float w3 = __shfl(w, 48 + i);
        acc0 += hv * w0; acc1 += hv * w1; acc2 += hv * w2; acc3 += hv * w3;
      }
    } else {
      for (int i = 0; i < cnt; ++i){
        int   si = __shfl(s, i);
        float hv = bu2f(h3[(size_t)si * 64 + lane]);
        float w0 = __shfl(w, i);
        float w1 = __shfl(w, 16 + i);
        float w2 = __shfl(w, 32 + i);
        float w3 = __shfl(w, 48 + i);
        acc0 += hv * w0; acc1 += hv * w1; acc2 += hv * w2; acc3 += hv * w3;
      }
    }
  }
  swp += __shfl_xor(swp, 1);
  swp += __shfl_xor(swp, 2);
  swp += __shfl_xor(swp, 4);
  swp += __shfl_xor(swp, 8);
  float sw0 = __shfl(swp, 0), sw1 = __shfl(swp, 16);
  float sw2 = __shfl(swp, 32), sw3 = __shfl(swp, 48);
  size_t zb = (size_t)node * 256;
  z[zb + lane]        = acc0 / sw0;
  z[zb + 64 + lane]   = acc1 / sw1;
  z[zb + 128 + lane]  = acc2 / sw2;
  z[zb + 192 + lane]  = acc3 / sw3;
}

// ---------------- pooling + head ----------------

__global__ void pool_k(const float* __restrict__ h, const int* __restrict__ fidx,
                       const int* __restrict__ flag_arr, float* __restrict__ fp, int m){
  __shared__ float acc[512];
  for (int t = threadIdx.x; t < 512; t += blockDim.x) acc[t] = 0.f;
  __syncthreads();
  int lane = threadIdx.x & 63;
  int wave = (blockIdx.x * blockDim.x + threadIdx.x) >> 6;
  int nwaves = (gridDim.x * blockDim.x) >> 6;
  for (int i = wave; i < m; i += nwaves){
    int g = flag_arr[i];
    int node = fidx[i];
    atomicAdd(&acc[g * 64 + lane], h[(size_t)node * 64 + lane]);
  }
  __syncthreads();
  for (int t = threadIdx.x; t < 512; t += blockDim.x)
    atomicAdd(&fp[t], acc[t]);
}

__global__ void final_k(const float* __restrict__ fp, const float* __restrict__ h,
                        const int* __restrict__ dec,
                        const float* __restrict__ Wp, const float* __restrict__ Wt,
                        const float* __restrict__ Wo, const float* __restrict__ bo,
                        void* __restrict__ out, const int* __restrict__ dflag){
  int g = threadIdx.x >> 6;
  int j = threadIdx.x & 63;
  const float* fr = fp + g * 64;
  const float* tr = h + (size_t)dec[g] * 64;
  float a = 0.f, b = 0.f;
  for (int k = 0; k < 64; ++k){
    a += fr[k] * Wp[k * 64 + j];
    b += tr[k] * Wt[k * 64 + j];
  }
  float v = eluf(a) * Wo[j] + eluf(b) * Wo[64 + j];
  for (int off = 32; off > 0; off >>= 1) v += __shfl_down(v, off);
  if (j == 0){
    float r = v + bo[0];
    if (*dflag) ((float*)out)[g] = r;
    else        ((bf16*)out)[g] = __float2bfloat16(r);
  }
}

// ---------------- launch (14 dispatches) ----------------

extern "C" void kernel_launch(void* const* d_in, const int* in_sizes, int n_in,
                              void* d_out, int out_size, void* d_ws, size_t ws_size,
                              hipStream_t stream) {
  const int*  ei    = (const int*)d_in[1];
  const int*  fidx  = (const int*)d_in[2];
  const int*  flagg = (const int*)d_in[3];
  const int*  dec   = (const int*)d_in[4];

  const int N = in_sizes[0] / 16;   // 20000
  const int E = in_sizes[1] / 2;    // 320000
  const int M = in_sizes[2];        // 8000
  const int ET = E + N;

  const int fidxs[21] = {0,5,6,7,8,9,10,11,12,13,14,15,16,17,18,19,20,21,22,23,24};
  ConvDesc cd;
  int tot = 0;
  for (int k = 0; k < 21; ++k){
    cd.src[k] = d_in[fidxs[k]];
    cd.off[k] = tot;
    tot += in_sizes[fidxs[k]];
  }
  cd.off[21] = tot;

  char* p = (char*)d_ws;
  auto carve = [&](size_t bytes) -> void* {
    void* r = (void*)p;
    p += (bytes + 255) & ~(size_t)255;
    return r;
  };
  int*   dflag   = (int*)carve(4);
  float* conv    = (float*)carve((size_t)tot * 4);
  u16*   hlA     = (u16*)carve((size_t)N * 64 * 2);   // bf16 h rows (L2-fit)
  u16*   hlB     = (u16*)carve((size_t)N * 64 * 2);
  u16*   h3buf   = (u16*)carve((size_t)N * 64 * 2);
  float* zbuf    = (float*)carve((size_t)N * 256 * 4);
  float* h4buf   = (float*)carve((size_t)N * 64 * 4);
  float* asrcA   = (float*)carve((size_t)N * 8 * 4);
  float* adstA   = (float*)carve((size_t)N * 8 * 4);
  float* asrcB   = (float*)carve((size_t)N * 8 * 4);
  float* adstB   = (float*)carve((size_t)N * 8 * 4);
  int*   counts  = (int*)carve((size_t)N * 4);
  int*   row_ptr = (int*)carve((size_t)(N + 1) * 4);
  int*   esrc    = (int*)carve((size_t)ET * 4);
  float* fp      = (float*)carve(8 * 64 * 4);
  float* avs     = (float*)carve(256 * 4);
  float* avd     = (float*)carve(256 * 4);
  float* wz      = (float*)carve(256 * 64 * 4);

  if ((size_t)(p - (char*)d_ws) > ws_size) return;

  const float* cW1 = conv + cd.off[1],  *cas1 = conv + cd.off[2],  *cad1 = conv + cd.off[3],  *cb1 = conv + cd.off[4];
  const float* cW2 = conv + cd.off[5],  *cas2 = conv + cd.off[6],  *cad2 = conv + cd.off[7],  *cb2 = conv + cd.off[8];
  const float* cW3 = conv + cd.off[9],  *cas3 = conv + cd.off[10], *cad3 = conv + cd.off[11], *cb3 = conv + cd.off[12];
  const float* cW4 = conv + cd.off[13], *cas4 = conv + cd.off[14], *cad4 = conv + cd.off[15], *cb4 = conv + cd.off[16];
  const float* cWp = conv + cd.off[17], *cWt = conv + cd.off[18], *cWo = conv + cd.off[19], *cbo = conv + cd.off[20];
  const float* xf  = conv + cd.off[0];

  const int TB = 256;

  int nprobe = in_sizes[0] < 4096 ? in_sizes[0] : 4096;
  detect_k<<<1, TB, 0, stream>>>((const u16*)d_in[0], nprobe, dflag);
  convert_all_k<<<(tot + TB - 1) / TB, TB, 0, stream>>>(cd, conv, dflag, tot, counts, fp, N);
  int eb = (ET + TB - 1) / TB;
  count_edges_k<<<eb, TB, 0, stream>>>(ei, counts, E, N);
  scan_k<<<1, 1024, 0, stream>>>(counts, counts, row_ptr, N);
  scatter_k<<<eb, TB, 0, stream>>>(ei, row_ptr, counts, esrc, E, N);
  prep4_k<<<64, TB, 0, stream>>>(cW4, cas4, cad4, avs, avd, wz);

  int agg_blocks = (N * 64 + TB - 1) / TB;
  int ls_blocks  = (N + 15) / 16;

  // layer-1 linear (bf16 out) + alpha1 -> A
  linear_s_k<16, false, true, true><<<ls_blocks, TB, 0, stream>>>(
      xf, cW1, nullptr, cas1, cad1, nullptr, hlA, asrcA, adstA, N);
  // agg1(A) + lin2 + alpha2 -> B
  agg8f_k<1><<<agg_blocks, TB, 0, stream>>>(hlA, asrcA, adstA, row_ptr, esrc, cb1,
                                            cW2, cas2, cad2, nullptr, nullptr,
                                            nullptr, hlB, asrcB, adstB, N);
  // agg2(B) + lin3 + alpha3 -> A
  agg8f_k<1><<<agg_blocks, TB, 0, stream>>>(hlB, asrcB, adstB, row_ptr, esrc, cb2,
                                            cW3, cas3, cad3, nullptr, nullptr,
                                            nullptr, hlA, asrcA, adstA, N);
  // agg3(A, stores h3 bf16) + alpha4 -> B
  agg8f_k<2><<<agg_blocks, TB, 0, stream>>>(hlA, asrcA, adstA, row_ptr, esrc, cb3,
                                            nullptr, nullptr, nullptr, avs, avd,
                                            h3buf, nullptr, asrcB, adstB, N);
  // layer-4 gather (B)
  aggz_k<<<agg_blocks, TB, 0, stream>>>(h3buf, asrcB, adstB, row_ptr, esrc, zbuf, N);
  // z @ Wz + bias + elu (fp32 out)
  linear_s_k<256, true, false, false><<<ls_blocks, TB, 0, stream>>>(
      zbuf, wz, cb4, nullptr, nullptr, h4buf, nullptr, nullptr, nullptr, N);
  // pool + head
  pool_k<<<64, TB, 0, stream>>>(h4buf, fidx, flagg, fp, M);
  final_k<<<1, 512, 0, stream>>>(fp, h4buf, dec, cWp, cWt, cWo, cbo, d_out, dflag);
}

// Round 13
// 335.766 us; speedup vs baseline: 1.4400x; 1.0908x over previous
//
#include <hip/hip_runtime.h>
#include <hip/hip_bf16.h>
#include <math.h>

typedef __hip_bfloat16 bf16;
typedef unsigned short u16;

__device__ __forceinline__ float b2f(bf16 v){ return __bfloat162float(v); }
__device__ __forceinline__ u16 f2bu(float f){
  bf16 h = __float2bfloat16(f);
  return *reinterpret_cast<u16*>(&h);
}
__device__ __forceinline__ float bu2f(u16 u){
  bf16 h = *reinterpret_cast<bf16*>(&u);
  return __bfloat162float(h);
}
__device__ __forceinline__ float eluf(float x){ return x > 0.f ? x : __expf(x) - 1.f; }
__device__ __forceinline__ float lrelu(float x){ return x > 0.f ? x : 0.2f * x; }

// ---------------- dtype detection ----------------
__global__ void detect_k(const u16* __restrict__ u16p, int n, int* __restrict__ flag){
  __shared__ int bad_s;
  if (threadIdx.x == 0) bad_s = 0;
  __syncthreads();
  int bad = 0;
  for (int k = threadIdx.x; k < n; k += 256){
    int ex = (u16p[k] >> 7) & 0xFF;
    if (ex >= 0xC6) bad = 1;
  }
  if (bad) atomicOr(&bad_s, 1);
  __syncthreads();
  if (threadIdx.x == 0) *flag = bad_s;
}

// ---------------- unified input conversion to fp32 (+ zero counts/fp) -------
struct ConvDesc {
  const void* src[21];
  int off[22];
};

__global__ void convert_all_k(ConvDesc d, float* __restrict__ out,
                              const int* __restrict__ flag, int total,
                              int* __restrict__ counts, float* __restrict__ fp, int n){
  int i = blockIdx.x * blockDim.x + threadIdx.x;
  if (i < n) counts[i] = 0;
  if (i < 512) fp[i] = 0.f;
  if (i >= total) return;
  int a = 0;
  while (i >= d.off[a + 1]) ++a;
  int j = i - d.off[a];
  float v;
  if (*flag) v = ((const float*)d.src[a])[j];
  else       v = b2f(((const bf16*)d.src[a])[j]);
  out[i] = v;
}

// ---------------- CSR build ----------------

__global__ void count_edges_k(const int* __restrict__ ei, int* __restrict__ counts, int E, int n){
  int e = blockIdx.x * blockDim.x + threadIdx.x;
  if (e >= E + n) return;
  int d = (e < E) ? ei[E + e] : (e - E);
  atomicAdd(&counts[d], 1);
}

__global__ void scan_k(const int* __restrict__ counts_in, int* __restrict__ counts_zero,
                       int* __restrict__ row_ptr, int n){
  __shared__ int psum[1024];
  int t = threadIdx.x;
  int chunk = (n + 1023) >> 10;
  int beg = t * chunk;
  int end = beg + chunk; if (end > n) end = n;
  int s = 0;
  for (int i = beg; i < end; ++i) s += counts_in[i];
  psum[t] = s;
  __syncthreads();
  for (int off = 1; off < 1024; off <<= 1){
    int v = (t >= off) ? psum[t - off] : 0;
    __syncthreads();
    psum[t] += v;
    __syncthreads();
  }
  int run = psum[t] - s;
  for (int i = beg; i < end; ++i){
    row_ptr[i] = run; run += counts_in[i]; counts_zero[i] = 0;
  }
  if (beg < n && end == n) row_ptr[n] = run;
}

__global__ void scatter_k(const int* __restrict__ ei, const int* __restrict__ row_ptr,
                          int* __restrict__ fill, int* __restrict__ esrc, int E, int n){
  int e = blockIdx.x * blockDim.x + threadIdx.x;
  if (e >= E + n) return;
  int s, d;
  if (e < E){ s = ei[e]; d = ei[E + e]; } else { s = e - E; d = s; }
  int pos = row_ptr[d] + atomicAdd(&fill[d], 1);
  esrc[pos] = s;
}

// ---------------- small-tile linear: 16 nodes/block ----------
// Round-13: X staged ROW-MAJOR (padded) so x reads are b128 — 5 DS-ops per
// 4 k-steps instead of 8 (DS-pipe is the bottleneck, see agg8f note).
template<int K, bool ELU, bool ALPHA, bool OB16>
__global__ void linear_s_k(const float* __restrict__ X, const float* __restrict__ W,
                           const float* __restrict__ bias,
                           const float* __restrict__ a_src, const float* __restrict__ a_dst,
                           float* __restrict__ Y, u16* __restrict__ Yb,
                           float* __restrict__ asrc, float* __restrict__ adst, int n){
  constexpr int KC = (K > 64) ? 64 : K;
  __shared__ float wl[KC * 64];
  __shared__ float xr[16][KC + 4];
  int base = blockIdx.x * 16;
  int t = threadIdx.x;
  int lane = t & 63, wv = t >> 6;
  int node = wv * 4 + (lane >> 4);
  int jj = lane & 15;
  float ax = 0.f, ay = 0.f, az = 0.f, aw = 0.f;
  for (int kb = 0; kb < K; kb += KC){
    if (kb) __syncthreads();
    for (int q = t; q < KC * 16; q += 256)
      ((float4*)wl)[q] = ((const float4*)(W + (size_t)(kb + (q >> 4)) * 64))[q & 15];
    for (int q = t; q < 16 * (KC / 4); q += 256){
      int nd = q / (KC / 4);
      int k4 = q - nd * (KC / 4);
      float4 v = make_float4(0.f, 0.f, 0.f, 0.f);
      if (base + nd < n) v = *(const float4*)(X + (size_t)(base + nd) * K + kb + k4 * 4);
      *(float4*)(&xr[nd][k4 * 4]) = v;
    }
    __syncthreads();
#pragma unroll 4
    for (int k4 = 0; k4 < KC / 4; ++k4){
      float4 xv = *(const float4*)(&xr[node][k4 * 4]);
      float4 w0 = ((const float4*)wl)[(k4 * 4 + 0) * 16 + jj];
      float4 w1 = ((const float4*)wl)[(k4 * 4 + 1) * 16 + jj];
      float4 w2 = ((const float4*)wl)[(k4 * 4 + 2) * 16 + jj];
      float4 w3 = ((const float4*)wl)[(k4 * 4 + 3) * 16 + jj];
      ax += xv.x * w0.x + xv.y * w1.x + xv.z * w2.x + xv.w * w3.x;
      ay += xv.x * w0.y + xv.y * w1.y + xv.z * w2.y + xv.w * w3.y;
      az += xv.x * w0.z + xv.y * w1.z + xv.z * w2.z + xv.w * w3.z;
      aw += xv.x * w0.w + xv.y * w1.w + xv.z * w2.w + xv.w * w3.w;
    }
  }
  int gn = base + node;
  if (gn < n){
    float vx = ax, vy = ay, vz = az, vw = aw;
    if (ELU){
      float4 b = ((const float4*)bias)[jj];
      vx = eluf(ax + b.x); vy = eluf(ay + b.y); vz = eluf(az + b.z); vw = eluf(aw + b.w);
    }
    if (OB16){
      ushort4 o4;
      o4.x = f2bu(vx); o4.y = f2bu(vy); o4.z = f2bu(vz); o4.w = f2bu(vw);
      ((ushort4*)(Yb + (size_t)gn * 64))[jj] = o4;
    } else {
      ((float4*)(Y + (size_t)gn * 64))[jj] = make_float4(vx, vy, vz, vw);
    }
  }
  if (ALPHA){
    float4 as = *(const float4*)(a_src + 4 * jj);
    float4 ad = *(const float4*)(a_dst + 4 * jj);
    float s1 = ax * as.x + ay * as.y + az * as.z + aw * as.w;
    float s2 = ax * ad.x + ay * ad.y + az * ad.z + aw * ad.w;
    s1 += __shfl_xor(s1, 1);
    s2 += __shfl_xor(s2, 1);
    if (gn < n){
      int h = jj >> 1;
      if ((jj & 1) == 0) asrc[gn * 8 + h] = s1;
      else               adst[gn * 8 + h] = s2;
    }
  }
}

// ---------------- layer-4 prep ----------------
__global__ void prep4_k(const float* __restrict__ W4, const float* __restrict__ as4,
                        const float* __restrict__ ad4, float* __restrict__ avs,
                        float* __restrict__ avd, float* __restrict__ Wz){
  int g = blockIdx.x * 256 + threadIdx.x;
  int r = g >> 6, c = g & 63;
  int h = r >> 6, k = r & 63;
  Wz[(size_t)r * 64 + c] = 0.25f * W4[(size_t)k * 256 + h * 64 + c];
  if (blockIdx.x == 0){
    int t = threadIdx.x;
    int th = t >> 6, tk = t & 63;
    const float* wr = W4 + (size_t)tk * 256 + th * 64;
    const float* sr = as4 + th * 64;
    const float* dr = ad4 + th * 64;
    float s1 = 0.f, s2 = 0.f;
    for (int cc = 0; cc < 64; ++cc){ float w = wr[cc]; s1 += w * sr[cc]; s2 += w * dr[cc]; }
    avs[t] = s1;
    avd[t] = s2;
  }
}

// ---------------- fused agg8 (bf16 h rows) ----------------------------------
// Round-13 epilogue v2: the old 64-step shfl-matmul was ~750 DS-pipe cyc/node
// (64 ds_bpermute + 64 ds_read). Now: o row -> LDS (same-wave RAW, no barrier
// needed), K-split quad ownership (lane = kk,jj): 16x(b32+b128) + 2 shfl
// reductions ~= 360 cyc/node. NEXT==2 alpha4 likewise via LDS partials.
template<int NEXT>
__global__ void agg8f_k(const u16* __restrict__ hlin, const float* __restrict__ asrc,
                        const float* __restrict__ adst, const int* __restrict__ row_ptr,
                        const int* __restrict__ esrc, const float* __restrict__ bias,
                        const float* __restrict__ Wn,
                        const float* __restrict__ a_srcn, const float* __restrict__ a_dstn,
                        const float* __restrict__ avs, const float* __restrict__ avd,
                        u16* __restrict__ hout, u16* __restrict__ ylin,
                        float* __restrict__ asrco, float* __restrict__ adsto, int n){
  __shared__ float wl[NEXT == 1 ? 4096 : 1];
  __shared__ float os[4][64];
  if (NEXT == 1){
    for (int q = threadIdx.x; q < 1024; q += 256)
      ((float4*)wl)[q] = ((const float4*)Wn)[q];
    __syncthreads();
  }
  int node = (blockIdx.x * blockDim.x + threadIdx.x) >> 6;
  if (node >= n) return;
  int lane = threadIdx.x & 63;
  int wv = (threadIdx.x >> 6) & 3;
  int h = lane >> 3;
  int j = lane & 7;
  int beg = row_ptr[node], end = row_ptr[node + 1];
  float ad = adst[node * 8 + h];
  int hb = lane & 56;

  float m = -INFINITY, acc = 0.f, swp = 0.f;
  int p0 = beg + j;
  int   s_nx = 0;
  float l_nx = -INFINITY;
  if (p0 < end){ s_nx = esrc[p0]; l_nx = lrelu(asrc[s_nx * 8 + h] + ad); }
  for (int b0 = beg; b0 < end; b0 += 8){
    int   s = s_nx;
    float l = l_nx;
    int p2 = b0 + 8 + j;
    s_nx = 0; l_nx = -INFINITY;
    if (p2 < end){ s_nx = esrc[p2]; l_nx = lrelu(asrc[s_nx * 8 + h] + ad); }
    float bm = l;
    bm = fmaxf(bm, __shfl_xor(bm, 1));
    bm = fmaxf(bm, __shfl_xor(bm, 2));
    bm = fmaxf(bm, __shfl_xor(bm, 4));
    float mn = fmaxf(m, bm);
    float scale = __expf(m - mn);
    acc *= scale; swp *= scale; m = mn;
    float w = (b0 + j < end) ? __expf(l - m) : 0.f;
    swp += w;
    int cnt = end - b0; if (cnt > 8) cnt = 8;
    if (cnt == 8){
#pragma unroll
      for (int i = 0; i < 8; ++i){
        int   si = __shfl(s, i);
        float hv = bu2f(hlin[(size_t)si * 64 + lane]);
        float wi = __shfl(w, hb + i);
        acc += hv * wi;
      }
    } else {
      for (int i = 0; i < cnt; ++i){
        int   si = __shfl(s, i);
        float hv = bu2f(hlin[(size_t)si * 64 + lane]);
        float wi = __shfl(w, hb + i);
        acc += hv * wi;
      }
    }
  }
  swp += __shfl_xor(swp, 1);
  swp += __shfl_xor(swp, 2);
  swp += __shfl_xor(swp, 4);
  float o = eluf(acc / swp + bias[lane]);

  if (NEXT == 1){
    os[wv][lane] = o;                 // same-wave RAW; compiler orders via lgkmcnt
    int jj = lane & 15, kk = lane >> 4;
    float ax = 0.f, ay = 0.f, az = 0.f, aw = 0.f;
#pragma unroll
    for (int k = 0; k < 16; ++k){
      float xv = os[wv][kk * 16 + k];
      float4 w = ((const float4*)wl)[(kk * 16 + k) * 16 + jj];
      ax += xv * w.x; ay += xv * w.y; az += xv * w.z; aw += xv * w.w;
    }
    ax += __shfl_xor(ax, 16); ax += __shfl_xor(ax, 32);
    ay += __shfl_xor(ay, 16); ay += __shfl_xor(ay, 32);
    az += __shfl_xor(az, 16); az += __shfl_xor(az, 32);
    aw += __shfl_xor(aw, 16); aw += __shfl_xor(aw, 32);
    if (lane < 16){
      ushort4 o4;
      o4.x = f2bu(ax); o4.y = f2bu(ay); o4.z = f2bu(az); o4.w = f2bu(aw);
      ((ushort4*)(ylin + (size_t)node * 64))[jj] = o4;
      float4 as = *(const float4*)(a_srcn + 4 * jj);
      float4 adn = *(const float4*)(a_dstn + 4 * jj);
      float s1 = ax * as.x + ay * as.y + az * as.z + aw * as.w;
      float s2 = ax * adn.x + ay * adn.y + az * adn.z + aw * adn.w;
      s1 += __shfl_xor(s1, 1);
      s2 += __shfl_xor(s2, 1);
      int hh = jj >> 1;
      if ((jj & 1) == 0) asrco[node * 8 + hh] = s1;
      else               adsto[node * 8 + hh] = s2;
    }
  } else {
    hout[(size_t)node * 64 + lane] = f2bu(o);
    os[wv][lane] = o;
    int t8 = lane & 7, hh = (lane >> 3) & 3, sd = lane >> 5;
    const float* av = sd ? avd : avs;
    float part = 0.f;
#pragma unroll
    for (int c = 0; c < 8; ++c)
      part += os[wv][t8 * 8 + c] * av[hh * 64 + t8 * 8 + c];
    part += __shfl_xor(part, 1);
    part += __shfl_xor(part, 2);
    part += __shfl_xor(part, 4);
    if (t8 == 0){
      if (sd == 0) asrco[node * 4 + hh] = part;
      else         adsto[node * 4 + hh] = part;
    }
  }
}

// Layer-4 gather (bf16 h3 rows). z stays fp32.
__global__ void aggz_k(const u16* __restrict__ h3, const float* __restrict__ asrc,
                       const float* __restrict__ adst, const int* __restrict__ row_ptr,
                       const int* __restrict__ esrc, float* __restrict__ z, int n){
  int node = (blockIdx.x * blockDim.x + threadIdx.x) >> 6;
  if (node >= n) return;
  int lane = threadIdx.x & 63;
  int h = lane >> 4, j = lane & 15;
  int beg = row_ptr[node], end = row_ptr[node + 1];
  float4 adv = *(const float4*)(adst + (size_t)node * 4);
  float adh = h == 0 ? adv.x : h == 1 ? adv.y : h == 2 ? adv.z : adv.w;

  float m = -INFINITY;
  float acc0 = 0.f, acc1 = 0.f, acc2 = 0.f, acc3 = 0.f, swp = 0.f;
  int p0 = beg + j;
  int   s_nx = 0;
  float l_nx = -INFINITY;
  if (p0 < end){ s_nx = esrc[p0]; l_nx = lrelu(asrc[s_nx * 4 + h] + adh); }
  for (int b0 = beg; b0 < end; b0 += 16){
    int   s = s_nx;
    float l = l_nx;
    int p2 = b0 + 16 + j;
    s_nx = 0; l_nx = -INFINITY;
    if (p2 < end){ s_nx = esrc[p2]; l_nx = lrelu(asrc[s_nx * 4 + h] + adh); }
    float bm = l;
    bm = fmaxf(bm, __shfl_xor(bm, 1));
    bm = fmaxf(bm, __shfl_xor(bm, 2));
    bm = fmaxf(bm, __shfl_xor(bm, 4));
    bm = fmaxf(bm, __shfl_xor(bm, 8));
    float mn = fmaxf(m, bm);
    float scale = __expf(m - mn);
    acc0 *= scale; acc1 *= scale; acc2 *= scale; acc3 *= scale;
    swp *= scale; m = mn;
    float w = (b0 + j < end) ? __expf(l - m) : 0.f;
    swp += w;
    int cnt = end - b0; if (cnt > 16) cnt = 16;
    if (cnt == 16){
#pragma unroll
      for (int i = 0; i < 16; ++i){
        int   si = __shfl(s, i);
        float hv = bu2f(h3[(size_t)si * 64 + lane]);
        float w0 = __shfl(w, i);
        float w1 = __shfl(w, 16 + i);
        float w2 = __shfl(w, 32 + i);
        float w3 = __shfl(w, 48 + i);
        acc0 += hv * w0; acc1 += hv * w1; acc2 += hv * w2; acc3 += hv * w3;
      }
    } else {
      for (int i = 0; i < cnt; ++i){
        int   si = __shfl(s, i);
        float hv = bu2f(h3[(size_t)si * 64 + lane]);
        float w0 = __shfl(w, i);
        float w1 = __shfl(w, 16 + i);
        float w2 = __shfl(w, 32 + i);
        float w3 = __shfl(w, 48 + i);
        acc0 += hv * w0; acc1 += hv * w1; acc2 += hv * w2; acc3 += hv * w3;
      }
    }
  }
  swp += __shfl_xor(swp, 1);
  swp += __shfl_xor(swp, 2);
  swp += __shfl_xor(swp, 4);
  swp += __shfl_xor(swp, 8);
  float sw0 = __shfl(swp, 0), sw1 = __shfl(swp, 16);
  float sw2 = __shfl(swp, 32), sw3 = __shfl(swp, 48);
  size_t zb = (size_t)node * 256;
  z[zb + lane]        = acc0 / sw0;
  z[zb + 64 + lane]   = acc1 / sw1;
  z[zb + 128 + lane]  = acc2 / sw2;
  z[zb + 192 + lane]  = acc3 / sw3;
}

// ---------------- pooling + head ----------------

__global__ void pool_k(const float* __restrict__ h, const int* __restrict__ fidx,
                       const int* __restrict__ flag_arr, float* __restrict__ fp, int m){
  __shared__ float acc[512];
  for (int t = threadIdx.x; t < 512; t += blockDim.x) acc[t] = 0.f;
  __syncthreads();
  int lane = threadIdx.x & 63;
  int wave = (blockIdx.x * blockDim.x + threadIdx.x) >> 6;
  int nwaves = (gridDim.x * blockDim.x) >> 6;
  for (int i = wave; i < m; i += nwaves){
    int g = flag_arr[i];
    int node = fidx[i];
    atomicAdd(&acc[g * 64 + lane], h[(size_t)node * 64 + lane]);
  }
  __syncthreads();
  for (int t = threadIdx.x; t < 512; t += blockDim.x)
    atomicAdd(&fp[t], acc[t]);
}

__global__ void final_k(const float* __restrict__ fp, const float* __restrict__ h,
                        const int* __restrict__ dec,
                        const float* __restrict__ Wp, const float* __restrict__ Wt,
                        const float* __restrict__ Wo, const float* __restrict__ bo,
                        void* __restrict__ out, const int* __restrict__ dflag){
  int g = threadIdx.x >> 6;
  int j = threadIdx.x & 63;
  const float* fr = fp + g * 64;
  const float* tr = h + (size_t)dec[g] * 64;
  float a = 0.f, b = 0.f;
  for (int k = 0; k < 64; ++k){
    a += fr[k] * Wp[k * 64 + j];
    b += tr[k] * Wt[k * 64 + j];
  }
  float v = eluf(a) * Wo[j] + eluf(b) * Wo[64 + j];
  for (int off = 32; off > 0; off >>= 1) v += __shfl_down(v, off);
  if (j == 0){
    float r = v + bo[0];
    if (*dflag) ((float*)out)[g] = r;
    else        ((bf16*)out)[g] = __float2bfloat16(r);
  }
}

// ---------------- launch (14 dispatches) ----------------

extern "C" void kernel_launch(void* const* d_in, const int* in_sizes, int n_in,
                              void* d_out, int out_size, void* d_ws, size_t ws_size,
                              hipStream_t stream) {
  const int*  ei    = (const int*)d_in[1];
  const int*  fidx  = (const int*)d_in[2];
  const int*  flagg = (const int*)d_in[3];
  const int*  dec   = (const int*)d_in[4];

  const int N = in_sizes[0] / 16;   // 20000
  const int E = in_sizes[1] / 2;    // 320000
  const int M = in_sizes[2];        // 8000
  const int ET = E + N;

  const int fidxs[21] = {0,5,6,7,8,9,10,11,12,13,14,15,16,17,18,19,20,21,22,23,24};
  ConvDesc cd;
  int tot = 0;
  for (int k = 0; k < 21; ++k){
    cd.src[k] = d_in[fidxs[k]];
    cd.off[k] = tot;
    tot += in_sizes[fidxs[k]];
  }
  cd.off[21] = tot;

  char* p = (char*)d_ws;
  auto carve = [&](size_t bytes) -> void* {
    void* r = (void*)p;
    p += (bytes + 255) & ~(size_t)255;
    return r;
  };
  int*   dflag   = (int*)carve(4);
  float* conv    = (float*)carve((size_t)tot * 4);
  u16*   hlA     = (u16*)carve((size_t)N * 64 * 2);   // bf16 h rows (L2-fit)
  u16*   hlB     = (u16*)carve((size_t)N * 64 * 2);
  u16*   h3buf   = (u16*)carve((size_t)N * 64 * 2);
  float* zbuf    = (float*)carve((size_t)N * 256 * 4);
  float* h4buf   = (float*)carve((size_t)N * 64 * 4);
  float* asrcA   = (float*)carve((size_t)N * 8 * 4);
  float* adstA   = (float*)carve((size_t)N * 8 * 4);
  float* asrcB   = (float*)carve((size_t)N * 8 * 4);
  float* adstB   = (float*)carve((size_t)N * 8 * 4);
  int*   counts  = (int*)carve((size_t)N * 4);
  int*   row_ptr = (int*)carve((size_t)(N + 1) * 4);
  int*   esrc    = (int*)carve((size_t)ET * 4);
  float* fp      = (float*)carve(8 * 64 * 4);
  float* avs     = (float*)carve(256 * 4);
  float* avd     = (float*)carve(256 * 4);
  float* wz      = (float*)carve(256 * 64 * 4);

  if ((size_t)(p - (char*)d_ws) > ws_size) return;

  const float* cW1 = conv + cd.off[1],  *cas1 = conv + cd.off[2],  *cad1 = conv + cd.off[3],  *cb1 = conv + cd.off[4];
  const float* cW2 = conv + cd.off[5],  *cas2 = conv + cd.off[6],  *cad2 = conv + cd.off[7],  *cb2 = conv + cd.off[8];
  const float* cW3 = conv + cd.off[9],  *cas3 = conv + cd.off[10], *cad3 = conv + cd.off[11], *cb3 = conv + cd.off[12];
  const float* cW4 = conv + cd.off[13], *cas4 = conv + cd.off[14], *cad4 = conv + cd.off[15], *cb4 = conv + cd.off[16];
  const float* cWp = conv + cd.off[17], *cWt = conv + cd.off[18], *cWo = conv + cd.off[19], *cbo = conv + cd.off[20];
  const float* xf  = conv + cd.off[0];

  const int TB = 256;

  int nprobe = in_sizes[0] < 4096 ? in_sizes[0] : 4096;
  detect_k<<<1, TB, 0, stream>>>((const u16*)d_in[0], nprobe, dflag);
  convert_all_k<<<(tot + TB - 1) / TB, TB, 0, stream>>>(cd, conv, dflag, tot, counts, fp, N);
  int eb = (ET + TB - 1) / TB;
  count_edges_k<<<eb, TB, 0, stream>>>(ei, counts, E, N);
  scan_k<<<1, 1024, 0, stream>>>(counts, counts, row_ptr, N);
  scatter_k<<<eb, TB, 0, stream>>>(ei, row_ptr, counts, esrc, E, N);
  prep4_k<<<64, TB, 0, stream>>>(cW4, cas4, cad4, avs, avd, wz);

  int agg_blocks = (N * 64 + TB - 1) / TB;
  int ls_blocks  = (N + 15) / 16;

  // layer-1 linear (bf16 out) + alpha1 -> A
  linear_s_k<16, false, true, true><<<ls_blocks, TB, 0, stream>>>(
      xf, cW1, nullptr, cas1, cad1, nullptr, hlA, asrcA, adstA, N);
  // agg1(A) + lin2 + alpha2 -> B
  agg8f_k<1><<<agg_blocks, TB, 0, stream>>>(hlA, asrcA, adstA, row_ptr, esrc, cb1,
                                            cW2, cas2, cad2, nullptr, nullptr,
                                            nullptr, hlB, asrcB, adstB, N);
  // agg2(B) + lin3 + alpha3 -> A
  agg8f_k<1><<<agg_blocks, TB, 0, stream>>>(hlB, asrcB, adstB, row_ptr, esrc, cb2,
                                            cW3, cas3, cad3, nullptr, nullptr,
                                            nullptr, hlA, asrcA, adstA, N);
  // agg3(A, stores h3 bf16) + alpha4 -> B
  agg8f_k<2><<<agg_blocks, TB, 0, stream>>>(hlA, asrcA, adstA, row_ptr, esrc, cb3,
                                            nullptr, nullptr, nullptr, avs, avd,
                                            h3buf, nullptr, asrcB, adstB, N);
  // layer-4 gather (B)
  aggz_k<<<agg_blocks, TB, 0, stream>>>(h3buf, asrcB, adstB, row_ptr, esrc, zbuf, N);
  // z @ Wz + bias + elu (fp32 out)
  linear_s_k<256, true, false, false><<<ls_blocks, TB, 0, stream>>>(
      zbuf, wz, cb4, nullptr, nullptr, h4buf, nullptr, nullptr, nullptr, N);
  // pool + head
  pool_k<<<64, TB, 0, stream>>>(h4buf, fidx, flagg, fp, M);
  final_k<<<1, 512, 0, stream>>>(fp, h4buf, dec, cWp, cWt, cWo, cbo, d_out, dflag);
}

// Round 14
// 322.472 us; speedup vs baseline: 1.4994x; 1.0412x over previous
//
#include <hip/hip_runtime.h>
#include <hip/hip_bf16.h>
#include <math.h>

typedef __hip_bfloat16 bf16;
typedef unsigned short u16;

__device__ __forceinline__ float b2f(bf16 v){ return __bfloat162float(v); }
__device__ __forceinline__ u16 f2bu(float f){
  bf16 h = __float2bfloat16(f);
  return *reinterpret_cast<u16*>(&h);
}
__device__ __forceinline__ float bu2f(u16 u){
  bf16 h = *reinterpret_cast<bf16*>(&u);
  return __bfloat162float(h);
}
__device__ __forceinline__ float eluf(float x){ return x > 0.f ? x : __expf(x) - 1.f; }
__device__ __forceinline__ float lrelu(float x){ return x > 0.f ? x : 0.2f * x; }
// flag-conditional raw input load (fp32 or bf16)
__device__ __forceinline__ float ldr(const void* p, int i, int f){
  return f ? ((const float*)p)[i] : b2f(((const bf16*)p)[i]);
}
__device__ __forceinline__ float rl_f(float v, int lane){
  return __int_as_float(__builtin_amdgcn_readlane(__float_as_int(v), lane));
}

// ---------------- detect dtype + zero counts/fp (merged) --------------------
__global__ void detect_zero_k(const u16* __restrict__ x, int nprobe, int* __restrict__ flag,
                              int* __restrict__ counts, float* __restrict__ fp, int n){
  int i = blockIdx.x * 256 + threadIdx.x;
  if (i < n) counts[i] = 0;
  if (i < 512) fp[i] = 0.f;
  if (blockIdx.x == 0){
    __shared__ int bad_s;
    if (threadIdx.x == 0) bad_s = 0;
    __syncthreads();
    int bad = 0;
    for (int k = threadIdx.x; k < nprobe; k += 256){
      int ex = (x[k] >> 7) & 0xFF;
      if (ex >= 0xC6) bad = 1;
    }
    if (bad) atomicOr(&bad_s, 1);
    __syncthreads();
    if (threadIdx.x == 0) *flag = bad_s;
  }
}

// ---------------- convert + count_edges + prep4 (merged) --------------------
struct ConvDesc {
  const void* src[21];
  int off[22];
};

__global__ void convcnt_k(ConvDesc d, float* __restrict__ out, const int* __restrict__ flag,
                          int total, const int* __restrict__ ei, int E, int n,
                          int* __restrict__ counts,
                          const void* __restrict__ W4r, const void* __restrict__ as4r,
                          const void* __restrict__ ad4r, float* __restrict__ avs,
                          float* __restrict__ avd, float* __restrict__ Wz,
                          int CB, int EB){
  int b = blockIdx.x;
  int f = *flag;
  if (b < CB){
    int i = b * 256 + threadIdx.x;
    if (i >= total) return;
    int a = 0;
    while (i >= d.off[a + 1]) ++a;
    out[i] = ldr(d.src[a], i - d.off[a], f);
  } else if (b < CB + EB){
    int e = (b - CB) * 256 + threadIdx.x;
    if (e >= E + n) return;
    int dd = (e < E) ? ei[E + e] : (e - E);
    atomicAdd(&counts[dd], 1);
  } else {
    int pb = b - CB - EB;                     // 0..63
    int g = pb * 256 + threadIdx.x;           // < 16384
    int r = g >> 6, c = g & 63;
    int h = r >> 6, k = r & 63;
    Wz[r * 64 + c] = 0.25f * ldr(W4r, k * 256 + h * 64 + c, f);
    if (pb == 0){
      int t = threadIdx.x;
      int th = t >> 6, tk = t & 63;
      float s1 = 0.f, s2 = 0.f;
      for (int cc = 0; cc < 64; ++cc){
        float w = ldr(W4r, tk * 256 + th * 64 + cc, f);
        s1 += w * ldr(as4r, th * 64 + cc, f);
        s2 += w * ldr(ad4r, th * 64 + cc, f);
      }
      avs[t] = s1;
      avd[t] = s2;
    }
  }
}

// ---------------- CSR scan + scatter ----------------

__global__ void scan_k(const int* __restrict__ counts_in, int* __restrict__ counts_zero,
                       int* __restrict__ row_ptr, int n){
  __shared__ int psum[1024];
  int t = threadIdx.x;
  int chunk = (n + 1023) >> 10;
  int beg = t * chunk;
  int end = beg + chunk; if (end > n) end = n;
  int s = 0;
  for (int i = beg; i < end; ++i) s += counts_in[i];
  psum[t] = s;
  __syncthreads();
  for (int off = 1; off < 1024; off <<= 1){
    int v = (t >= off) ? psum[t - off] : 0;
    __syncthreads();
    psum[t] += v;
    __syncthreads();
  }
  int run = psum[t] - s;
  for (int i = beg; i < end; ++i){
    row_ptr[i] = run; run += counts_in[i]; counts_zero[i] = 0;
  }
  if (beg < n && end == n) row_ptr[n] = run;
}

__global__ void scatter_k(const int* __restrict__ ei, const int* __restrict__ row_ptr,
                          int* __restrict__ fill, int* __restrict__ esrc, int E, int n){
  int e = blockIdx.x * blockDim.x + threadIdx.x;
  if (e >= E + n) return;
  int s, d;
  if (e < E){ s = ei[e]; d = ei[E + e]; } else { s = e - E; d = s; }
  int pos = row_ptr[d] + atomicAdd(&fill[d], 1);
  esrc[pos] = s;
}

// ---------------- small-tile linear: 16 nodes/block ----------
// IB16: X in bf16 (for z@Wz); OB16: Y stored bf16 (h arrays, L2-fit).
template<int K, bool ELU, bool ALPHA, bool OB16, bool IB16>
__global__ void linear_s_k(const float* __restrict__ Xf, const u16* __restrict__ Xb,
                           const float* __restrict__ W, const float* __restrict__ bias,
                           const float* __restrict__ a_src, const float* __restrict__ a_dst,
                           float* __restrict__ Y, u16* __restrict__ Yb,
                           float* __restrict__ asrc, float* __restrict__ adst, int n){
  constexpr int KC = (K > 64) ? 64 : K;
  __shared__ float wl[KC * 64];
  __shared__ float xr[16][KC + 4];
  int base = blockIdx.x * 16;
  int t = threadIdx.x;
  int lane = t & 63, wv = t >> 6;
  int node = wv * 4 + (lane >> 4);
  int jj = lane & 15;
  float ax = 0.f, ay = 0.f, az = 0.f, aw = 0.f;
  for (int kb = 0; kb < K; kb += KC){
    if (kb) __syncthreads();
    for (int q = t; q < KC * 16; q += 256)
      ((float4*)wl)[q] = ((const float4*)(W + (kb + (q >> 4)) * 64))[q & 15];
    for (int q = t; q < 16 * (KC / 4); q += 256){
      int nd = q / (KC / 4);
      int k4 = q - nd * (KC / 4);
      if (IB16){
        float4 v = make_float4(0.f, 0.f, 0.f, 0.f);
        if (base + nd < n){
          ushort4 v4 = *(const ushort4*)(Xb + (base + nd) * K + kb + k4 * 4);
          v = make_float4(bu2f(v4.x), bu2f(v4.y), bu2f(v4.z), bu2f(v4.w));
        }
        *(float4*)(&xr[nd][k4 * 4]) = v;
      } else {
        float4 v = make_float4(0.f, 0.f, 0.f, 0.f);
        if (base + nd < n) v = *(const float4*)(Xf + (base + nd) * K + kb + k4 * 4);
        *(float4*)(&xr[nd][k4 * 4]) = v;
      }
    }
    __syncthreads();
#pragma unroll 4
    for (int k4 = 0; k4 < KC / 4; ++k4){
      float4 xv = *(const float4*)(&xr[node][k4 * 4]);
      float4 w0 = ((const float4*)wl)[(k4 * 4 + 0) * 16 + jj];
      float4 w1 = ((const float4*)wl)[(k4 * 4 + 1) * 16 + jj];
      float4 w2 = ((const float4*)wl)[(k4 * 4 + 2) * 16 + jj];
      float4 w3 = ((const float4*)wl)[(k4 * 4 + 3) * 16 + jj];
      ax += xv.x * w0.x + xv.y * w1.x + xv.z * w2.x + xv.w * w3.x;
      ay += xv.x * w0.y + xv.y * w1.y + xv.z * w2.y + xv.w * w3.y;
      az += xv.x * w0.z + xv.y * w1.z + xv.z * w2.z + xv.w * w3.z;
      aw += xv.x * w0.w + xv.y * w1.w + xv.z * w2.w + xv.w * w3.w;
    }
  }
  int gn = base + node;
  if (gn < n){
    float vx = ax, vy = ay, vz = az, vw = aw;
    if (ELU){
      float4 b = ((const float4*)bias)[jj];
      vx = eluf(ax + b.x); vy = eluf(ay + b.y); vz = eluf(az + b.z); vw = eluf(aw + b.w);
    }
    if (OB16){
      ushort4 o4;
      o4.x = f2bu(vx); o4.y = f2bu(vy); o4.z = f2bu(vz); o4.w = f2bu(vw);
      ((ushort4*)(Yb + gn * 64))[jj] = o4;
    } else {
      ((float4*)(Y + gn * 64))[jj] = make_float4(vx, vy, vz, vw);
    }
  }
  if (ALPHA){
    float4 as = *(const float4*)(a_src + 4 * jj);
    float4 ad = *(const float4*)(a_dst + 4 * jj);
    float s1 = ax * as.x + ay * as.y + az * as.z + aw * as.w;
    float s2 = ax * ad.x + ay * ad.y + az * ad.z + aw * ad.w;
    s1 += __shfl_xor(s1, 1);
    s2 += __shfl_xor(s2, 1);
    if (gn < n){
      int h = jj >> 1;
      if ((jj & 1) == 0) asrc[gn * 8 + h] = s1;
      else               adst[gn * 8 + h] = s2;
    }
  }
}

// ---------------- fused agg8 (bf16 h rows) ----------------------------------
// Round-14: s broadcasts via v_readlane (SGPR, zero DS; uniform si gives
// scalar row addresses); w broadcasts via immediate ds_swizzle (kills index
// VALU). 32-bit indexing throughout. Alpha ping-pong preserved.
#define A8_STEP(I) { \
    int si = __builtin_amdgcn_readlane(s, I); \
    float hv = bu2f(hlin[si * 64 + lane]); \
    float wi = __int_as_float(__builtin_amdgcn_ds_swizzle(__float_as_int(w), ((I) << 5) | 0x18)); \
    acc += hv * wi; }

template<int NEXT>
__global__ void agg8f_k(const u16* __restrict__ hlin, const float* __restrict__ asrc,
                        const float* __restrict__ adst, const int* __restrict__ row_ptr,
                        const int* __restrict__ esrc, const float* __restrict__ bias,
                        const float* __restrict__ Wn,
                        const float* __restrict__ a_srcn, const float* __restrict__ a_dstn,
                        const float* __restrict__ avs, const float* __restrict__ avd,
                        u16* __restrict__ hout, u16* __restrict__ ylin,
                        float* __restrict__ asrco, float* __restrict__ adsto, int n){
  __shared__ float wl[NEXT == 1 ? 4096 : 1];
  __shared__ float os[4][64];
  if (NEXT == 1){
    for (int q = threadIdx.x; q < 1024; q += 256)
      ((float4*)wl)[q] = ((const float4*)Wn)[q];
    __syncthreads();
  }
  int node = (blockIdx.x * blockDim.x + threadIdx.x) >> 6;
  if (node >= n) return;
  int lane = threadIdx.x & 63;
  int wv = (threadIdx.x >> 6) & 3;
  int h = lane >> 3;
  int j = lane & 7;
  int beg = row_ptr[node], end = row_ptr[node + 1];
  float ad = adst[node * 8 + h];
  int hb = lane & 56;

  float m = -INFINITY, acc = 0.f, swp = 0.f;
  int p0 = beg + j;
  int   s_nx = 0;
  float l_nx = -INFINITY;
  if (p0 < end){ s_nx = esrc[p0]; l_nx = lrelu(asrc[s_nx * 8 + h] + ad); }
  for (int b0 = beg; b0 < end; b0 += 8){
    int   s = s_nx;
    float l = l_nx;
    int p2 = b0 + 8 + j;
    s_nx = 0; l_nx = -INFINITY;
    if (p2 < end){ s_nx = esrc[p2]; l_nx = lrelu(asrc[s_nx * 8 + h] + ad); }
    float bm = l;
    bm = fmaxf(bm, __shfl_xor(bm, 1));
    bm = fmaxf(bm, __shfl_xor(bm, 2));
    bm = fmaxf(bm, __shfl_xor(bm, 4));
    float mn = fmaxf(m, bm);
    float scale = __expf(m - mn);
    acc *= scale; swp *= scale; m = mn;
    float w = (b0 + j < end) ? __expf(l - m) : 0.f;
    swp += w;
    int cnt = end - b0; if (cnt > 8) cnt = 8;
    if (cnt == 8){
      A8_STEP(0) A8_STEP(1) A8_STEP(2) A8_STEP(3)
      A8_STEP(4) A8_STEP(5) A8_STEP(6) A8_STEP(7)
    } else {
      for (int i = 0; i < cnt; ++i){
        int   si = __builtin_amdgcn_readlane(s, i);
        float hv = bu2f(hlin[si * 64 + lane]);
        float wi = __shfl(w, hb + i);
        acc += hv * wi;
      }
    }
  }
  swp += __shfl_xor(swp, 1);
  swp += __shfl_xor(swp, 2);
  swp += __shfl_xor(swp, 4);
  float o = eluf(acc / swp + bias[lane]);

  if (NEXT == 1){
    os[wv][lane] = o;
    int jj = lane & 15, kk = lane >> 4;
    float ax = 0.f, ay = 0.f, az = 0.f, aw = 0.f;
#pragma unroll
    for (int k = 0; k < 16; ++k){
      float xv = os[wv][kk * 16 + k];
      float4 w = ((const float4*)wl)[(kk * 16 + k) * 16 + jj];
      ax += xv * w.x; ay += xv * w.y; az += xv * w.z; aw += xv * w.w;
    }
    ax += __shfl_xor(ax, 16); ax += __shfl_xor(ax, 32);
    ay += __shfl_xor(ay, 16); ay += __shfl_xor(ay, 32);
    az += __shfl_xor(az, 16); az += __shfl_xor(az, 32);
    aw += __shfl_xor(aw, 16); aw += __shfl_xor(aw, 32);
    if (lane < 16){
      ushort4 o4;
      o4.x = f2bu(ax); o4.y = f2bu(ay); o4.z = f2bu(az); o4.w = f2bu(aw);
      ((ushort4*)(ylin + node * 64))[jj] = o4;
      float4 as = *(const float4*)(a_srcn + 4 * jj);
      float4 adn = *(const float4*)(a_dstn + 4 * jj);
      float s1 = ax * as.x + ay * as.y + az * as.z + aw * as.w;
      float s2 = ax * adn.x + ay * adn.y + az * adn.z + aw * adn.w;
      s1 += __shfl_xor(s1, 1);
      s2 += __shfl_xor(s2, 1);
      int hh = jj >> 1;
      if ((jj & 1) == 0) asrco[node * 8 + hh] = s1;
      else               adsto[node * 8 + hh] = s2;
    }
  } else {
    hout[node * 64 + lane] = f2bu(o);
    os[wv][lane] = o;
    int t8 = lane & 7, hh = (lane >> 3) & 3, sd = lane >> 5;
    const float* av = sd ? avd : avs;
    float part = 0.f;
#pragma unroll
    for (int c = 0; c < 8; ++c)
      part += os[wv][t8 * 8 + c] * av[hh * 64 + t8 * 8 + c];
    part += __shfl_xor(part, 1);
    part += __shfl_xor(part, 2);
    part += __shfl_xor(part, 4);
    if (t8 == 0){
      if (sd == 0) asrco[node * 4 + hh] = part;
      else         adsto[node * 4 + hh] = part;
    }
  }
}

// Layer-4 gather: s AND all 4 per-edge weights via readlane (uniform lanes) —
// DS ops per 16-edge batch drop ~84 -> 4. z stored bf16.
__global__ void aggz_k(const u16* __restrict__ h3, const float* __restrict__ asrc,
                       const float* __restrict__ adst, const int* __restrict__ row_ptr,
                       const int* __restrict__ esrc, u16* __restrict__ z, int n){
  int node = (blockIdx.x * blockDim.x + threadIdx.x) >> 6;
  if (node >= n) return;
  int lane = threadIdx.x & 63;
  int h = lane >> 4, j = lane & 15;
  int beg = row_ptr[node], end = row_ptr[node + 1];
  float4 adv = *(const float4*)(adst + node * 4);
  float adh = h == 0 ? adv.x : h == 1 ? adv.y : h == 2 ? adv.z : adv.w;

  float m = -INFINITY;
  float acc0 = 0.f, acc1 = 0.f, acc2 = 0.f, acc3 = 0.f, swp = 0.f;
  int p0 = beg + j;
  int   s_nx = 0;
  float l_nx = -INFINITY;
  if (p0 < end){ s_nx = esrc[p0]; l_nx = lrelu(asrc[s_nx * 4 + h] + adh); }
  for (int b0 = beg; b0 < end; b0 += 16){
    int   s = s_nx;
    float l = l_nx;
    int p2 = b0 + 16 + j;
    s_nx = 0; l_nx = -INFINITY;
    if (p2 < end){ s_nx = esrc[p2]; l_nx = lrelu(asrc[s_nx * 4 + h] + adh); }
    float bm = l;
    bm = fmaxf(bm, __shfl_xor(bm, 1));
    bm = fmaxf(bm, __shfl_xor(bm, 2));
    bm = fmaxf(bm, __shfl_xor(bm, 4));
    bm = fmaxf(bm, __shfl_xor(bm, 8));
    float mn = fmaxf(m, bm);
    float scale = __expf(m - mn);
    acc0 *= scale; acc1 *= scale; acc2 *= scale; acc3 *= scale;
    swp *= scale; m = mn;
    float w = (b0 + j < end) ? __expf(l - m) : 0.f;
    swp += w;
    int cnt = end - b0; if (cnt > 16) cnt = 16;
#pragma unroll 4
    for (int i = 0; i < cnt; ++i){
      int   si = __builtin_amdgcn_readlane(s, i);
      float hv = bu2f(h3[si * 64 + lane]);
      float w0 = rl_f(w, i);
      float w1 = rl_f(w, 16 + i);
      float w2 = rl_f(w, 32 + i);
      float w3 = rl_f(w, 48 + i);
      acc0 += hv * w0; acc1 += hv * w1; acc2 += hv * w2; acc3 += hv * w3;
    }
  }
  swp += __shfl_xor(swp, 1);
  swp += __shfl_xor(swp, 2);
  swp += __shfl_xor(swp, 4);
  swp += __shfl_xor(swp, 8);
  float sw0 = __shfl(swp, 0), sw1 = __shfl(swp, 16);
  float sw2 = __shfl(swp, 32), sw3 = __shfl(swp, 48);
  int zb = node * 256;
  z[zb + lane]        = f2bu(acc0 / sw0);
  z[zb + 64 + lane]   = f2bu(acc1 / sw1);
  z[zb + 128 + lane]  = f2bu(acc2 / sw2);
  z[zb + 192 + lane]  = f2bu(acc3 / sw3);
}

// ---------------- pooling + head ----------------

__global__ void pool_k(const float* __restrict__ h, const int* __restrict__ fidx,
                       const int* __restrict__ flag_arr, float* __restrict__ fp, int m){
  __shared__ float acc[512];
  for (int t = threadIdx.x; t < 512; t += blockDim.x) acc[t] = 0.f;
  __syncthreads();
  int lane = threadIdx.x & 63;
  int wave = (blockIdx.x * blockDim.x + threadIdx.x) >> 6;
  int nwaves = (gridDim.x * blockDim.x) >> 6;
  for (int i = wave; i < m; i += nwaves){
    int g = flag_arr[i];
    int node = fidx[i];
    atomicAdd(&acc[g * 64 + lane], h[node * 64 + lane]);
  }
  __syncthreads();
  for (int t = threadIdx.x; t < 512; t += blockDim.x)
    atomicAdd(&fp[t], acc[t]);
}

__global__ void final_k(const float* __restrict__ fp, const float* __restrict__ h,
                        const int* __restrict__ dec,
                        const float* __restrict__ Wp, const float* __restrict__ Wt,
                        const float* __restrict__ Wo, const float* __restrict__ bo,
                        void* __restrict__ out, const int* __restrict__ dflag){
  int g = threadIdx.x >> 6;
  int j = threadIdx.x & 63;
  const float* fr = fp + g * 64;
  const float* tr = h + dec[g] * 64;
  float a = 0.f, b = 0.f;
  for (int k = 0; k < 64; ++k){
    a += fr[k] * Wp[k * 64 + j];
    b += tr[k] * Wt[k * 64 + j];
  }
  float v = eluf(a) * Wo[j] + eluf(b) * Wo[64 + j];
  for (int off = 32; off > 0; off >>= 1) v += __shfl_down(v, off);
  if (j == 0){
    float r = v + bo[0];
    if (*dflag) ((float*)out)[g] = r;
    else        ((bf16*)out)[g] = __float2bfloat16(r);
  }
}

// ---------------- launch (12 dispatches) ----------------

extern "C" void kernel_launch(void* const* d_in, const int* in_sizes, int n_in,
                              void* d_out, int out_size, void* d_ws, size_t ws_size,
                              hipStream_t stream) {
  const int*  ei    = (const int*)d_in[1];
  const int*  fidx  = (const int*)d_in[2];
  const int*  flagg = (const int*)d_in[3];
  const int*  dec   = (const int*)d_in[4];

  const int N = in_sizes[0] / 16;   // 20000
  const int E = in_sizes[1] / 2;    // 320000
  const int M = in_sizes[2];        // 8000
  const int ET = E + N;

  const int fidxs[21] = {0,5,6,7,8,9,10,11,12,13,14,15,16,17,18,19,20,21,22,23,24};
  ConvDesc cd;
  int tot = 0;
  for (int k = 0; k < 21; ++k){
    cd.src[k] = d_in[fidxs[k]];
    cd.off[k] = tot;
    tot += in_sizes[fidxs[k]];
  }
  cd.off[21] = tot;

  char* p = (char*)d_ws;
  auto carve = [&](size_t bytes) -> void* {
    void* r = (void*)p;
    p += (bytes + 255) & ~(size_t)255;
    return r;
  };
  int*   dflag   = (int*)carve(4);
  float* conv    = (float*)carve((size_t)tot * 4);
  u16*   hlA     = (u16*)carve((size_t)N * 64 * 2);
  u16*   hlB     = (u16*)carve((size_t)N * 64 * 2);
  u16*   h3buf   = (u16*)carve((size_t)N * 64 * 2);
  u16*   zbuf    = (u16*)carve((size_t)N * 256 * 2);
  float* h4buf   = (float*)carve((size_t)N * 64 * 4);
  float* asrcA   = (float*)carve((size_t)N * 8 * 4);
  float* adstA   = (float*)carve((size_t)N * 8 * 4);
  float* asrcB   = (float*)carve((size_t)N * 8 * 4);
  float* adstB   = (float*)carve((size_t)N * 8 * 4);
  int*   counts  = (int*)carve((size_t)N * 4);
  int*   row_ptr = (int*)carve((size_t)(N + 1) * 4);
  int*   esrc    = (int*)carve((size_t)ET * 4);
  float* fp      = (float*)carve(8 * 64 * 4);
  float* avs     = (float*)carve(256 * 4);
  float* avd     = (float*)carve(256 * 4);
  float* wz      = (float*)carve(256 * 64 * 4);

  if ((size_t)(p - (char*)d_ws) > ws_size) return;

  const float* cW1 = conv + cd.off[1],  *cas1 = conv + cd.off[2],  *cad1 = conv + cd.off[3],  *cb1 = conv + cd.off[4];
  const float* cW2 = conv + cd.off[5],  *cas2 = conv + cd.off[6],  *cad2 = conv + cd.off[7],  *cb2 = conv + cd.off[8];
  const float* cW3 = conv + cd.off[9],  *cas3 = conv + cd.off[10], *cad3 = conv + cd.off[11], *cb3 = conv + cd.off[12];
  const float* cb4 = conv + cd.off[16];
  const float* cWp = conv + cd.off[17], *cWt = conv + cd.off[18], *cWo = conv + cd.off[19], *cbo = conv + cd.off[20];
  const float* xf  = conv + cd.off[0];

  const int TB = 256;
  int nprobe = in_sizes[0] < 4096 ? in_sizes[0] : 4096;
  int zb_blocks = (N + 255) / 256;            // >= 2 (covers 512 fp slots)
  int CB = (tot + 255) / 256;
  int EB = (ET + 255) / 256;

  // 1: detect + zero counts/fp
  detect_zero_k<<<zb_blocks, TB, 0, stream>>>((const u16*)d_in[0], nprobe, dflag, counts, fp, N);
  // 2: convert + count_edges + prep4
  convcnt_k<<<CB + EB + 64, TB, 0, stream>>>(cd, conv, dflag, tot, ei, E, N, counts,
                                             d_in[17], d_in[18], d_in[19], avs, avd, wz, CB, EB);
  // 3-4: scan + scatter
  scan_k<<<1, 1024, 0, stream>>>(counts, counts, row_ptr, N);
  scatter_k<<<EB, TB, 0, stream>>>(ei, row_ptr, counts, esrc, E, N);

  int agg_blocks = (N * 64 + TB - 1) / TB;
  int ls_blocks  = (N + 15) / 16;

  // 5: layer-1 linear (bf16 out) + alpha1 -> A
  linear_s_k<16, false, true, true, false><<<ls_blocks, TB, 0, stream>>>(
      xf, nullptr, cW1, nullptr, cas1, cad1, nullptr, hlA, asrcA, adstA, N);
  // 6: agg1(A) + lin2 + alpha2 -> B
  agg8f_k<1><<<agg_blocks, TB, 0, stream>>>(hlA, asrcA, adstA, row_ptr, esrc, cb1,
                                            cW2, cas2, cad2, nullptr, nullptr,
                                            nullptr, hlB, asrcB, adstB, N);
  // 7: agg2(B) + lin3 + alpha3 -> A
  agg8f_k<1><<<agg_blocks, TB, 0, stream>>>(hlB, asrcB, adstB, row_ptr, esrc, cb2,
                                            cW3, cas3, cad3, nullptr, nullptr,
                                            nullptr, hlA, asrcA, adstA, N);
  // 8: agg3(A, stores h3 bf16) + alpha4 -> B
  agg8f_k<2><<<agg_blocks, TB, 0, stream>>>(hlA, asrcA, adstA, row_ptr, esrc, cb3,
                                            nullptr, nullptr, nullptr, avs, avd,
                                            h3buf, nullptr, asrcB, adstB, N);
  // 9: layer-4 gather (B) -> z bf16
  aggz_k<<<agg_blocks, TB, 0, stream>>>(h3buf, asrcB, adstB, row_ptr, esrc, zbuf, N);
  // 10: z @ Wz + bias + elu (bf16 in, fp32 out)
  linear_s_k<256, true, false, false, true><<<ls_blocks, TB, 0, stream>>>(
      nullptr, zbuf, wz, cb4, nullptr, nullptr, h4buf, nullptr, nullptr, nullptr, N);
  // 11-12: pool + head
  pool_k<<<64, TB, 0, stream>>>(h4buf, fidx, flagg, fp, M);
  final_k<<<1, 512, 0, stream>>>(fp, h4buf, dec, cWp, cWt, cWo, cbo, d_out, dflag);
}